// Round 16
// baseline (449.761 us; speedup 1.0000x reference)
//
#include <hip/hip_runtime.h>

#define NB   16
#define NN   2048
#define NPTS (NB * NN)
#define KNB  6

typedef __attribute__((ext_vector_type(8))) short short8;
typedef __attribute__((ext_vector_type(2))) float f32x2;
typedef __attribute__((ext_vector_type(4))) float f32x4;
typedef __attribute__((ext_vector_type(16))) float f32x16;
typedef const __attribute__((address_space(4))) float cfloat;
typedef const __attribute__((address_space(4))) f32x2 cf32x2;

__device__ __forceinline__ unsigned bf16_rne(float f) {
    unsigned u = __float_as_uint(f);
    return (u + 0x7fffu + ((u >> 16) & 1u)) >> 16;
}

// ---------------- prep: bf16 hi/lo split + |x|^2 ONLY (verified R15) ----------------
template<int C>
__global__ __launch_bounds__(256)
void prep_split(const float* __restrict__ x,
                unsigned short* __restrict__ Xhi,
                unsigned short* __restrict__ Xlo,
                float* __restrict__ sq) {
    const int tid  = threadIdx.x;
    const int slot = tid & 3;
    const int i    = blockIdx.x * 64 + (tid >> 2);
    constexpr int Q = C / 4;

    float r[Q];
    const float4* rp = (const float4*)(x + (size_t)i * C + slot * Q);
#pragma unroll
    for (int c4 = 0; c4 < Q / 4; ++c4) {
        float4 f = rp[c4];
        r[4 * c4] = f.x; r[4 * c4 + 1] = f.y; r[4 * c4 + 2] = f.z; r[4 * c4 + 3] = f.w;
    }
    float s = 0.f;
#pragma unroll
    for (int c = 0; c < Q; ++c) s = fmaf(r[c], r[c], s);
    s += __shfl_xor(s, 1);
    s += __shfl_xor(s, 2);
    if (slot == 0) sq[i] = s;

#pragma unroll
    for (int cc = 0; cc < Q; cc += 8) {
        short8 vh, vl;
#pragma unroll
        for (int t = 0; t < 8; ++t) {
            const float f = r[cc + t];
            const unsigned h = bf16_rne(f);
            const float hf = __uint_as_float(h << 16);
            vh[t] = (short)h;
            vl[t] = (short)bf16_rne(f - hf);
        }
        *(short8*)(Xhi + (size_t)i * C + slot * Q + cc) = vh;
        *(short8*)(Xlo + (size_t)i * C + slot * Q + cc) = vl;
    }
}

// ---------------- weight prep: bf16 hi/lo of combined [2COUT][C] GEMM weights (verified R15) ----------------
__global__ void prep_w(const float* __restrict__ W10, const float* __restrict__ W11,
                       const float* __restrict__ W12,
                       unsigned short* __restrict__ Whi0, unsigned short* __restrict__ Wlo0,
                       unsigned short* __restrict__ Whi1, unsigned short* __restrict__ Wlo1,
                       unsigned short* __restrict__ Whi2, unsigned short* __restrict__ Wlo2) {
    int t = blockIdx.x * 256 + threadIdx.x;
    if (t >= 4096) return;
    {   // L0 / L2: n = t>>5 in [0,128), k = t&31
        const int n = t >> 5, k = t & 31;
        float v0, v2;
        if (n < 64) { v0 = W10[k * 64 + n] - W10[(32 + k) * 64 + n];
                      v2 = W12[k * 64 + n] - W12[(32 + k) * 64 + n]; }
        else        { v0 = W10[(32 + k) * 64 + (n - 64)];
                      v2 = W12[(32 + k) * 64 + (n - 64)]; }
        unsigned h0 = bf16_rne(v0);
        Whi0[t] = (unsigned short)h0;
        Wlo0[t] = (unsigned short)bf16_rne(v0 - __uint_as_float(h0 << 16));
        unsigned h2 = bf16_rne(v2);
        Whi2[t] = (unsigned short)h2;
        Wlo2[t] = (unsigned short)bf16_rne(v2 - __uint_as_float(h2 << 16));
    }
    {   // L1: n = t>>6 in [0,64), k = t&63
        const int n = t >> 6, k = t & 63;
        float v;
        if (n < 32) v = W11[k * 32 + n] - W11[(64 + k) * 32 + n];
        else        v = W11[(64 + k) * 32 + (n - 32)];
        unsigned h = bf16_rne(v);
        Whi1[t] = (unsigned short)h;
        Wlo1[t] = (unsigned short)bf16_rne(v - __uint_as_float(h << 16));
    }
}

// ---------------- AB GEMM (verified R15) ----------------
template<int C, int COUT>
__global__ __launch_bounds__(256, 2)
void ab_gemm(const unsigned short* __restrict__ Xhi,
             const unsigned short* __restrict__ Xlo,
             const unsigned short* __restrict__ Whi,
             const unsigned short* __restrict__ Wlo,
             const float* __restrict__ b1, float* __restrict__ AB) {
    constexpr int KT  = C / 16;
    constexpr int N2  = 2 * COUT;
    constexpr int NCT = N2 / 32;            // col tiles: 4 (L0/2), 2 (L1)
    constexpr int RPB = 4 / NCT;            // row tiles per block
    const int w    = __builtin_amdgcn_readfirstlane(threadIdx.x >> 6);
    const int lane = threadIdx.x & 63;
    const int n31  = lane & 31;
    const int lh   = lane >> 5;
    const int rt   = blockIdx.x * RPB + w / NCT;
    const int ct   = w % NCT;
    const int p0   = rt * 32;

    short8 ah[KT], al[KT], wh[KT], wl[KT];
#pragma unroll
    for (int kt = 0; kt < KT; ++kt) {
        const size_t poff = (size_t)(p0 + n31) * C + kt * 16 + lh * 8;
        ah[kt] = *(const short8*)(Xhi + poff);
        al[kt] = *(const short8*)(Xlo + poff);
        const size_t woff = (size_t)(ct * 32 + n31) * C + kt * 16 + lh * 8;
        wh[kt] = *(const short8*)(Whi + woff);
        wl[kt] = *(const short8*)(Wlo + woff);
    }

    f32x16 acc = {0.f};
#pragma unroll
    for (int kt = 0; kt < KT; ++kt) {
        acc = __builtin_amdgcn_mfma_f32_32x32x16_bf16(ah[kt], wh[kt], acc, 0, 0, 0);
        acc = __builtin_amdgcn_mfma_f32_32x32x16_bf16(ah[kt], wl[kt], acc, 0, 0, 0);
        acc = __builtin_amdgcn_mfma_f32_32x32x16_bf16(al[kt], wh[kt], acc, 0, 0, 0);
    }

    const int nc = ct * 32 + n31;           // output col in [0, 2COUT)
    const float bias = (ct < COUT / 32) ? b1[nc] : 0.f;   // A-tile test is wave-uniform
#pragma unroll
    for (int r = 0; r < 16; ++r) {
        const int pt = p0 + (r & 3) + 8 * (r >> 2) + 4 * lh;
        AB[(size_t)pt * N2 + nc] = acc[r] + bias;
    }
}

// sorted ascending top-6 insert via pure min/max network (2 VALU / level).
__device__ __forceinline__ void insert6f(float s, float* dl) {
#pragma unroll
    for (int k = 0; k < 6; ++k) {
        const float a = dl[k];
        dl[k] = fminf(s, a);
        s = fmaxf(s, a);
    }
}

// ---------------- MFMA kNN scan (8-way split, LDS-staged candidates) ----------------
// R15 PMC: MfmaUtil 18 + VALU 55, Occ 27% (grid-capped at 4 blocks/CU,
// barrier-synced quads idle the SIMDs). The LDS redesign left VGPR at 48,
// so 8 blocks/CU is now reachable (R8's register-resident version spilled).
// wave = 32 queries x 256 candidates (eighth sp); grid 2048 = 8 blocks/CU.
// plist -> 16 sublists x 6 u32 (z = sp*2+lh). Staging/swizzle/vmcnt
// machinery identical to the verified R9/R15 kernel; only the split changed.
template<int C, int MINW>
__global__ __launch_bounds__(256, MINW)
void knn_scan(const unsigned short* __restrict__ Xhi,
              const unsigned short* __restrict__ Xlo,
              const float* __restrict__ sqv,
              unsigned* __restrict__ plist) {
    constexpr int KT    = C / 16;           // K=16 tiles per product
    constexpr int SR    = C / 4;            // 16B slots per LDS row (hi+lo)
    constexpr int ROWB  = SR * 16;          // 128 / 256 bytes per row
    constexpr int STEPB = 32 * ROWB;        // 4 KB / 8 KB per step buffer
    constexpr int LPT   = STEPB / 16 / 256; // 1 / 2 loads per thread per step
    __shared__ __align__(16) char sm[2 * STEPB];

    const int tid  = threadIdx.x;
    const int w    = __builtin_amdgcn_readfirstlane(tid >> 6);
    const int bid  = blockIdx.x;
    const int swz  = ((bid & 7) << 8) | (bid >> 3);   // 2048 blocks, 256/XCD
    const int b    = swz >> 7;              // batch (2 per XCD)
    const int sp   = (swz >> 4) & 7;        // candidate eighth
    const int qg   = swz & 15;              // query group of 4 tiles
    const int qt   = qg * 4 + w;            // this wave's query tile (32 q)
    const int lane = tid & 63;
    const int q31  = lane & 31;
    const int lh   = lane >> 5;
    const int base = b * NN;
    const int qloc = qt * 32 + q31;         // batch-local query index

    // persistent query fragments
    short8 bh[KT], bl[KT];
#pragma unroll
    for (int kt = 0; kt < KT; ++kt) {
        const size_t off = (size_t)(base + qloc) * C + kt * 16 + lh * 8;
        bh[kt] = *(const short8*)(Xhi + off);
        bl[kt] = *(const short8*)(Xlo + off);
    }

    float dl[6];
#pragma unroll
    for (int k = 0; k < 6; ++k) dl[k] = 1e30f;

    const int jbeg   = sp * (NN / 8);
    const int selfjb = qt * 32;             // only step that can contain self

    // staging source pointers: thread's LDS slot sidx -> (row, slot);
    // content = SRC[row][slot ^ (row&(SR-1))] (XOR involution; reader undoes it)
    const unsigned short* src[LPT];
#pragma unroll
    for (int l = 0; l < LPT; ++l) {
        const int sidx = tid + l * 256;
        const int row  = sidx / SR;
        const int slot = sidx % SR;
        const int u    = slot ^ (row & (SR - 1));
        const unsigned short* bp = (u < SR / 2) ? Xhi : Xlo;
        src[l] = bp + (size_t)(base + jbeg + row) * C + (u & (SR / 2 - 1)) * 8;
    }

    // per-lane ds-read constants
    const int m       = q31 & (SR - 1);
    const int rowbase = q31 * ROWB;
    const float* sqp  = sqv + base + jbeg + lh * 4;
    float4 s4[4];

#define STAGE(BUF) do {                                                        \
    _Pragma("unroll")                                                          \
    for (int l = 0; l < LPT; ++l) {                                            \
        __builtin_amdgcn_global_load_lds(                                      \
            (const __attribute__((address_space(1))) void*)src[l],             \
            (__attribute__((address_space(3))) void*)                          \
                (sm + (BUF) * STEPB + l * 4096 + w * 1024),                    \
            16, 0, 0);                                                         \
        src[l] += 32 * C;                                                      \
    }                                                                          \
} while (0)

#define COMPUTE(BUF, JB) do {                                                  \
    const char* smc = sm + (BUF) * STEPB;                                      \
    f32x16 acc = {0.f};                                                        \
    _Pragma("unroll")                                                          \
    for (int kt = 0; kt < KT; ++kt) {                                          \
        const int uh = kt * 2 + lh;                                            \
        const int ul = 2 * KT + kt * 2 + lh;                                   \
        const short8 ah = *(const short8*)(smc + rowbase + ((uh ^ m) << 4));   \
        const short8 al = *(const short8*)(smc + rowbase + ((ul ^ m) << 4));   \
        acc = __builtin_amdgcn_mfma_f32_32x32x16_bf16(ah, bh[kt], acc, 0, 0, 0); \
        acc = __builtin_amdgcn_mfma_f32_32x32x16_bf16(ah, bl[kt], acc, 0, 0, 0); \
        acc = __builtin_amdgcn_mfma_f32_32x32x16_bf16(al, bh[kt], acc, 0, 0, 0); \
    }                                                                          \
    const unsigned ebase = (unsigned)(((JB) - jbeg) >> 1);   /* step*16 */     \
    const bool selfstep = ((JB) == selfjb);                                    \
    _Pragma("unroll")                                                          \
    for (int g4 = 0; g4 < 4; ++g4) {                                           \
        _Pragma("unroll")                                                      \
        for (int rr = 0; rr < 4; ++rr) {                                       \
            const int r = g4 * 4 + rr;                                         \
            float sc = fmaf(-2.f, acc[r],                                      \
                rr == 0 ? s4[g4].x : rr == 1 ? s4[g4].y :                      \
                rr == 2 ? s4[g4].z : s4[g4].w);                                \
            sc = __uint_as_float((__float_as_uint(sc) & 0xFFFFFF00u) |         \
                                 (ebase + (unsigned)((r & 3) + 4 * (r >> 2)))); \
            if (selfstep) {                                                    \
                const int rowr = (r & 3) + 8 * (r >> 2) + 4 * lh;              \
                sc = (rowr == q31) ? 1e30f : sc;                               \
            }                                                                  \
            insert6f(sc, dl);                                                  \
        }                                                                      \
    }                                                                          \
} while (0)

    STAGE(0);                               // prologue: step 0 in flight
    int jb = jbeg, cur = 0;
#pragma unroll 1
    for (int st = 0; st < 7; ++st) {
        __builtin_amdgcn_s_barrier();       // WAR: all waves done reading buf cur^1
#pragma unroll
        for (int g4 = 0; g4 < 4; ++g4) s4[g4] = *(const float4*)(sqp + g4 * 8);
        asm volatile("" ::: "memory");      // pin: sq loads issue BEFORE stage
        STAGE(cur ^ 1);                     // step st+1 in flight
        if constexpr (C == 32) asm volatile("s_waitcnt vmcnt(1)" ::: "memory");
        else                   asm volatile("s_waitcnt vmcnt(2)" ::: "memory");
        __builtin_amdgcn_s_barrier();       // RAW: all waves' step-st data landed
        COMPUTE(cur, jb);
        jb += 32; sqp += 32; cur ^= 1;
    }
    {   // epilogue: last step, drain
        __builtin_amdgcn_s_barrier();
#pragma unroll
        for (int g4 = 0; g4 < 4; ++g4) s4[g4] = *(const float4*)(sqp + g4 * 8);
        asm volatile("s_waitcnt vmcnt(0)" ::: "memory");
        __builtin_amdgcn_s_barrier();
        COMPUTE(cur, jb);
    }
#undef STAGE
#undef COMPUTE

    // write this lane's sorted sublist as sortable-transformed u32 keys
    unsigned* o = plist + (size_t)(base + qloc) * 96 + (sp * 2 + lh) * 6;
#pragma unroll
    for (int k = 0; k < 6; ++k) {
        const unsigned bits = __float_as_uint(dl[k]);
        o[k] = bits ^ ((bits & 0x80000000u) ? 0xFFFFFFFFu : 0x80000000u);
    }
}

// ---------------- exact rescore: 2 threads/query, 8 sublists each ----------------
// slot = gi&1; slot 0 covers sp 0..3 (z 0..7), slot 1 covers sp 4..7 --
// disjoint candidate halves. Merge 8 sorted 6-sublists -> approx top-7
// (cushion 1 over per-half exact top-6), exact-rescore 7, keep exact top-6,
// exchange via shfl_xor, both compute final top-6 of 12; each writes 3.
template<int C>
__global__ __launch_bounds__(256)
void rescore(const float* __restrict__ x, const float* __restrict__ sqv,
             const unsigned* __restrict__ plist, int* __restrict__ nbr) {
    const int bid  = blockIdx.x;
    const int bsw  = ((bid & 7) << 5) | (bid >> 3);   // 256 blocks, bijective
    const int gi   = bsw * 256 + threadIdx.x;
    const int i    = gi >> 1;
    const int slot = gi & 1;

    const unsigned* pr = plist + (size_t)i * 96 + slot * 48;

    unsigned long long best[7];
#pragma unroll
    for (int k = 0; k < 7; ++k) best[k] = ~0ull;
    for (int z8 = 0; z8 < 8; ++z8) {
        const unsigned* p = pr + z8 * 6;
        const unsigned zg = (unsigned)(slot * 8 + z8);
        for (int e = 0; e < 6; ++e) {
            unsigned long long v = ((unsigned long long)p[e] << 4) | zg;
            if (v >= best[6]) break;      // sublist ascending
            best[6] = v;
#pragma unroll
            for (int k = 5; k >= 0; --k) {
                if (best[k + 1] < best[k]) {
                    unsigned long long t = best[k]; best[k] = best[k + 1]; best[k + 1] = t;
                }
            }
        }
    }

    const int base = i & ~(NN - 1);
    float4 qv[C / 4];
    const float4* qp = (const float4*)(x + (size_t)i * C);
#pragma unroll
    for (int t = 0; t < C / 4; ++t) qv[t] = qp[t];

    unsigned long long out6[6];
#pragma unroll
    for (int k = 0; k < 6; ++k) out6[k] = ~0ull;

    for (int m = 0; m < 7; ++m) {
        const unsigned u32k = (unsigned)(best[m] >> 4);
        const int z = (int)(best[m] & 15ull);
        const unsigned orig = (u32k & 0x80000000u) ? (u32k ^ 0x80000000u) : ~u32k;
        const int e = (int)(orig & 255u);
        const int idx = e & 15;
        const int jloc = (z >> 1) * (NN / 8) + (e >> 4) * 32 +
                         (idx & 3) + 8 * (idx >> 2) + (z & 1) * 4;

        const float4* cp = (const float4*)(x + (size_t)(base + jloc) * C);
        float d0 = 0.f, d1 = 0.f, d2 = 0.f, d3 = 0.f;
#pragma unroll
        for (int t = 0; t < C / 4; ++t) {
            float4 a = cp[t];
            d0 = fmaf(a.x, qv[t].x, d0);
            d1 = fmaf(a.y, qv[t].y, d1);
            d2 = fmaf(a.z, qv[t].z, d2);
            d3 = fmaf(a.w, qv[t].w, d3);
        }
        const float s = fmaf(-2.f, (d0 + d1) + (d2 + d3), sqv[base + jloc]);
        unsigned u = __float_as_uint(s);
        u ^= (u & 0x80000000u) ? 0xFFFFFFFFu : 0x80000000u;
        unsigned long long key = ((unsigned long long)u << 11) | (unsigned)jloc;
#pragma unroll
        for (int k = 0; k < 6; ++k) {
            const unsigned long long ok = out6[k];
            const bool c = key < ok;
            out6[k] = c ? key : ok;
            key     = c ? ok  : key;
        }
    }

    // exchange per-half exact top-6 with partner; merge to final top-6
    unsigned long long fin[6];
#pragma unroll
    for (int k = 0; k < 6; ++k) fin[k] = out6[k];
#pragma unroll
    for (int k = 0; k < 6; ++k) {
        const unsigned long long v = out6[k];
        const unsigned lo = __shfl_xor((unsigned)v, 1);
        const unsigned hi = __shfl_xor((unsigned)(v >> 32), 1);
        unsigned long long key = ((unsigned long long)hi << 32) | lo;
#pragma unroll
        for (int q = 0; q < 6; ++q) {
            const unsigned long long ok = fin[q];
            const bool c = key < ok;
            fin[q] = c ? key : ok;
            key    = c ? ok  : key;
        }
    }
#pragma unroll
    for (int k = 0; k < 3; ++k)
        nbr[i * KNB + slot * 3 + k] = base + (int)(fin[slot * 3 + k] & 2047ull);
}

// ---------------- edge MLP kernel (gathered A/B from the MFMA-computed AB; verified R15) ----------------
template<int COUT, bool RESID, int MINW>
__global__ __launch_bounds__(768, MINW)
void mlp_kernel(const float* __restrict__ AB, const int* __restrict__ nbr,
                const float* __restrict__ W2, const float* __restrict__ b2,
                const float* __restrict__ resid, float* __restrict__ out) {
    constexpr int HALF = COUT / 2;
    constexpr int NQ   = COUT / 4;
    constexpr int N2   = 2 * COUT;
    constexpr int RS = HALF + 4;
    __shared__ float Buf[2][3][64][RS];

    const int tid  = threadIdx.x;
    const int lane = tid & 63;
    const int wv   = __builtin_amdgcn_readfirstlane(tid >> 6);  // 0..11
    const int oh   = wv / 6;                                    // output half
    const int w6   = wv % 6;                                    // neighbor
    const int bid  = blockIdx.x;
    const int bsw  = ((bid & 7) << 6) | (bid >> 3);             // XCD swizzle, 512 blocks
    const int i    = bsw * 64 + lane;
    const int j    = nbr[i * KNB + w6];

    f32x2 uacc[HALF / 2];
#pragma unroll
    for (int o = 0; o < HALF / 2; ++o) uacc[o] = (f32x2){0.f, 0.f};

    cfloat* W2c = (cfloat*)(uintptr_t)W2;
    const float* Ap = AB + (size_t)i * N2;
    const float* Bp = AB + (size_t)j * N2 + COUT;

    const int qofs = (wv * 3) & (NQ - 1);    // wave-staggered op start

#pragma unroll 2
    for (int qi = 0; qi < NQ; ++qi) {
        const int oq = (qi + qofs) & (NQ - 1);
        const float4 a4 = *(const float4*)(Ap + 4 * oq);
        const float4 b4 = *(const float4*)(Bp + 4 * oq);
#pragma unroll
        for (int rr = 0; rr < 4; ++rr) {
            const int op = oq * 4 + rr;
            const float aop = rr == 0 ? a4.x : rr == 1 ? a4.y : rr == 2 ? a4.z : a4.w;
            const float bop = rr == 0 ? b4.x : rr == 1 ? b4.y : rr == 2 ? b4.z : b4.w;
            const float h = fmaxf(aop + bop, 0.f);
            cf32x2* w2p = (cf32x2*)(W2c + (size_t)op * COUT + oh * HALF);
            const f32x2 hv = {h, h};
#pragma unroll
            for (int o = 0; o < HALF / 2; ++o)
                uacc[o] += w2p[o] * hv;          // v_pk_fma_f32
        }
    }

    // per-half 6 -> 1 max tree over neighbor waves
    if (w6 >= 3) {
#pragma unroll
        for (int o = 0; o < HALF / 2; ++o) {
            Buf[oh][w6 - 3][lane][2 * o]     = uacc[o].x;
            Buf[oh][w6 - 3][lane][2 * o + 1] = uacc[o].y;
        }
    }
    __syncthreads();
    if (w6 < 3) {
#pragma unroll
        for (int o = 0; o < HALF / 2; ++o) {
            uacc[o].x = fmaxf(uacc[o].x, Buf[oh][w6][lane][2 * o]);
            uacc[o].y = fmaxf(uacc[o].y, Buf[oh][w6][lane][2 * o + 1]);
        }
    }
    __syncthreads();
    if (w6 == 1 || w6 == 2) {
#pragma unroll
        for (int o = 0; o < HALF / 2; ++o) {
            Buf[oh][w6][lane][2 * o]     = uacc[o].x;
            Buf[oh][w6][lane][2 * o + 1] = uacc[o].y;
        }
    }
    __syncthreads();
    if (w6 == 0) {
        float* po = out + (size_t)i * COUT + oh * HALF;
        const float* b2p = b2 + oh * HALF;
        const float* rp  = RESID ? (resid + (size_t)i * COUT + oh * HALF) : nullptr;
#pragma unroll
        for (int o = 0; o < HALF / 2; ++o) {
            float v0 = fmaxf(uacc[o].x,
                             fmaxf(Buf[oh][1][lane][2 * o], Buf[oh][2][lane][2 * o])) + b2p[2 * o];
            float v1 = fmaxf(uacc[o].y,
                             fmaxf(Buf[oh][1][lane][2 * o + 1], Buf[oh][2][lane][2 * o + 1])) + b2p[2 * o + 1];
            if (RESID) { v0 += rp[2 * o]; v1 += rp[2 * o + 1]; }
            po[2 * o]     = fmaxf(v0, 0.f);
            po[2 * o + 1] = fmaxf(v1, 0.f);
        }
    }
}

extern "C" void kernel_launch(void* const* d_in, const int* in_sizes, int n_in,
                              void* d_out, int out_size, void* d_ws, size_t ws_size,
                              hipStream_t stream) {
    const float* x    = (const float*)d_in[0];
    const float* W1_0 = (const float*)d_in[2];
    const float* b1_0 = (const float*)d_in[3];
    const float* W2_0 = (const float*)d_in[4];
    const float* b2_0 = (const float*)d_in[5];
    const float* W1_1 = (const float*)d_in[6];
    const float* b1_1 = (const float*)d_in[7];
    const float* W2_1 = (const float*)d_in[8];
    const float* b2_1 = (const float*)d_in[9];
    const float* W1_2 = (const float*)d_in[10];
    const float* b1_2 = (const float*)d_in[11];
    const float* W2_2 = (const float*)d_in[12];
    const float* b2_2 = (const float*)d_in[13];
    float* outp = (float*)d_out;

    // workspace layout
    unsigned* plist = (unsigned*)d_ws;                            // NPTS*96 u32
    float* x0  = (float*)(plist + (size_t)NPTS * 96);             // 32768 x 64
    float* x1  = x0 + (size_t)NPTS * 64;                          // 32768 x 32
    float* sqb = x1 + (size_t)NPTS * 32;                          // 32768
    unsigned short* Whi0 = (unsigned short*)(sqb + NPTS);         // 6 x 4096 u16
    unsigned short* Wlo0 = Whi0 + 4096;
    unsigned short* Whi1 = Wlo0 + 4096;
    unsigned short* Wlo1 = Whi1 + 4096;
    unsigned short* Whi2 = Wlo1 + 4096;
    unsigned short* Wlo2 = Whi2 + 4096;
    unsigned short* Xhi = Wlo2 + 4096;                            // 32768 x 64 u16
    unsigned short* Xlo = Xhi + (size_t)NPTS * 64;                // 32768 x 64 u16
    int* nbr = (int*)(Xlo + (size_t)NPTS * 64);                   // 32768 x 6
    float* AB = (float*)(nbr + (size_t)NPTS * KNB);               // 32768 x 128

    const int fgrid  = NPTS / 64;       // prep_split: 4 thr/point, 512 blocks
    const int rgrid  = NPTS * 2 / 256;  // rescore: 2 thr/query, 256 blocks
    const int scgrid = 2048;            // 8192 waves of 32q x 256c -> 8 blocks/CU
    const int pgrid  = NPTS / 64;       // 512 blocks x 768 thr

    prep_w<<<16, 256, 0, stream>>>(W1_0, W1_1, W1_2, Whi0, Wlo0, Whi1, Wlo1, Whi2, Wlo2);

    // ---- layer 0: x (32) -> x0 (64), relu ----
    prep_split<32><<<fgrid, 256, 0, stream>>>(x, Xhi, Xlo, sqb);
    ab_gemm<32, 64><<<NPTS / 32, 256, 0, stream>>>(Xhi, Xlo, Whi0, Wlo0, b1_0, AB);
    knn_scan<32, 8><<<scgrid, 256, 0, stream>>>(Xhi, Xlo, sqb, plist);
    rescore<32><<<rgrid, 256, 0, stream>>>(x, sqb, plist, nbr);
    mlp_kernel<64, false, 5><<<pgrid, 768, 0, stream>>>(AB, nbr, W2_0, b2_0, nullptr, x0);

    // ---- layer 1: x0 (64) -> x1 (32), relu ----
    prep_split<64><<<fgrid, 256, 0, stream>>>(x0, Xhi, Xlo, sqb);
    ab_gemm<64, 32><<<NPTS / 64, 256, 0, stream>>>(Xhi, Xlo, Whi1, Wlo1, b1_1, AB);
    knn_scan<64, 6><<<scgrid, 256, 0, stream>>>(Xhi, Xlo, sqb, plist);
    rescore<64><<<rgrid, 256, 0, stream>>>(x0, sqb, plist, nbr);
    mlp_kernel<32, false, 4><<<pgrid, 768, 0, stream>>>(AB, nbr, W2_1, b2_1, nullptr, x1);

    // ---- layer 2: x1 (32) -> out (64), +x0 residual, relu ----
    prep_split<32><<<fgrid, 256, 0, stream>>>(x1, Xhi, Xlo, sqb);
    ab_gemm<32, 64><<<NPTS / 32, 256, 0, stream>>>(Xhi, Xlo, Whi2, Wlo2, b1_2, AB);
    knn_scan<32, 8><<<scgrid, 256, 0, stream>>>(Xhi, Xlo, sqb, plist);
    rescore<32><<<rgrid, 256, 0, stream>>>(x1, sqb, plist, nbr);
    mlp_kernel<64, true, 5><<<pgrid, 768, 0, stream>>>(AB, nbr, W2_2, b2_2, x0, outp);
}

// Round 17
// 406.485 us; speedup vs baseline: 1.1065x; 1.1065x over previous
//
#include <hip/hip_runtime.h>

#define NB   16
#define NN   2048
#define NPTS (NB * NN)
#define KNB  6

typedef __attribute__((ext_vector_type(8))) short short8;
typedef __attribute__((ext_vector_type(2))) float f32x2;
typedef __attribute__((ext_vector_type(4))) float f32x4;
typedef __attribute__((ext_vector_type(16))) float f32x16;
typedef const __attribute__((address_space(4))) float cfloat;
typedef const __attribute__((address_space(4))) f32x2 cf32x2;

__device__ __forceinline__ unsigned bf16_rne(float f) {
    unsigned u = __float_as_uint(f);
    return (u + 0x7fffu + ((u >> 16) & 1u)) >> 16;
}

// ---------------- prep: bf16 hi/lo split + |x|^2 ONLY (verified R15) ----------------
template<int C>
__global__ __launch_bounds__(256)
void prep_split(const float* __restrict__ x,
                unsigned short* __restrict__ Xhi,
                unsigned short* __restrict__ Xlo,
                float* __restrict__ sq) {
    const int tid  = threadIdx.x;
    const int slot = tid & 3;
    const int i    = blockIdx.x * 64 + (tid >> 2);
    constexpr int Q = C / 4;

    float r[Q];
    const float4* rp = (const float4*)(x + (size_t)i * C + slot * Q);
#pragma unroll
    for (int c4 = 0; c4 < Q / 4; ++c4) {
        float4 f = rp[c4];
        r[4 * c4] = f.x; r[4 * c4 + 1] = f.y; r[4 * c4 + 2] = f.z; r[4 * c4 + 3] = f.w;
    }
    float s = 0.f;
#pragma unroll
    for (int c = 0; c < Q; ++c) s = fmaf(r[c], r[c], s);
    s += __shfl_xor(s, 1);
    s += __shfl_xor(s, 2);
    if (slot == 0) sq[i] = s;

#pragma unroll
    for (int cc = 0; cc < Q; cc += 8) {
        short8 vh, vl;
#pragma unroll
        for (int t = 0; t < 8; ++t) {
            const float f = r[cc + t];
            const unsigned h = bf16_rne(f);
            const float hf = __uint_as_float(h << 16);
            vh[t] = (short)h;
            vl[t] = (short)bf16_rne(f - hf);
        }
        *(short8*)(Xhi + (size_t)i * C + slot * Q + cc) = vh;
        *(short8*)(Xlo + (size_t)i * C + slot * Q + cc) = vl;
    }
}

// ---------------- weight prep: bf16 hi/lo of combined [2COUT][C] GEMM weights (verified R15) ----------------
__global__ void prep_w(const float* __restrict__ W10, const float* __restrict__ W11,
                       const float* __restrict__ W12,
                       unsigned short* __restrict__ Whi0, unsigned short* __restrict__ Wlo0,
                       unsigned short* __restrict__ Whi1, unsigned short* __restrict__ Wlo1,
                       unsigned short* __restrict__ Whi2, unsigned short* __restrict__ Wlo2) {
    int t = blockIdx.x * 256 + threadIdx.x;
    if (t >= 4096) return;
    {   // L0 / L2: n = t>>5 in [0,128), k = t&31
        const int n = t >> 5, k = t & 31;
        float v0, v2;
        if (n < 64) { v0 = W10[k * 64 + n] - W10[(32 + k) * 64 + n];
                      v2 = W12[k * 64 + n] - W12[(32 + k) * 64 + n]; }
        else        { v0 = W10[(32 + k) * 64 + (n - 64)];
                      v2 = W12[(32 + k) * 64 + (n - 64)]; }
        unsigned h0 = bf16_rne(v0);
        Whi0[t] = (unsigned short)h0;
        Wlo0[t] = (unsigned short)bf16_rne(v0 - __uint_as_float(h0 << 16));
        unsigned h2 = bf16_rne(v2);
        Whi2[t] = (unsigned short)h2;
        Wlo2[t] = (unsigned short)bf16_rne(v2 - __uint_as_float(h2 << 16));
    }
    {   // L1: n = t>>6 in [0,64), k = t&63
        const int n = t >> 6, k = t & 63;
        float v;
        if (n < 32) v = W11[k * 32 + n] - W11[(64 + k) * 32 + n];
        else        v = W11[(64 + k) * 32 + (n - 32)];
        unsigned h = bf16_rne(v);
        Whi1[t] = (unsigned short)h;
        Wlo1[t] = (unsigned short)bf16_rne(v - __uint_as_float(h << 16));
    }
}

// ---------------- AB GEMM (verified R15) ----------------
template<int C, int COUT>
__global__ __launch_bounds__(256, 2)
void ab_gemm(const unsigned short* __restrict__ Xhi,
             const unsigned short* __restrict__ Xlo,
             const unsigned short* __restrict__ Whi,
             const unsigned short* __restrict__ Wlo,
             const float* __restrict__ b1, float* __restrict__ AB) {
    constexpr int KT  = C / 16;
    constexpr int N2  = 2 * COUT;
    constexpr int NCT = N2 / 32;            // col tiles: 4 (L0/2), 2 (L1)
    constexpr int RPB = 4 / NCT;            // row tiles per block
    const int w    = __builtin_amdgcn_readfirstlane(threadIdx.x >> 6);
    const int lane = threadIdx.x & 63;
    const int n31  = lane & 31;
    const int lh   = lane >> 5;
    const int rt   = blockIdx.x * RPB + w / NCT;
    const int ct   = w % NCT;
    const int p0   = rt * 32;

    short8 ah[KT], al[KT], wh[KT], wl[KT];
#pragma unroll
    for (int kt = 0; kt < KT; ++kt) {
        const size_t poff = (size_t)(p0 + n31) * C + kt * 16 + lh * 8;
        ah[kt] = *(const short8*)(Xhi + poff);
        al[kt] = *(const short8*)(Xlo + poff);
        const size_t woff = (size_t)(ct * 32 + n31) * C + kt * 16 + lh * 8;
        wh[kt] = *(const short8*)(Whi + woff);
        wl[kt] = *(const short8*)(Wlo + woff);
    }

    f32x16 acc = {0.f};
#pragma unroll
    for (int kt = 0; kt < KT; ++kt) {
        acc = __builtin_amdgcn_mfma_f32_32x32x16_bf16(ah[kt], wh[kt], acc, 0, 0, 0);
        acc = __builtin_amdgcn_mfma_f32_32x32x16_bf16(ah[kt], wl[kt], acc, 0, 0, 0);
        acc = __builtin_amdgcn_mfma_f32_32x32x16_bf16(al[kt], wh[kt], acc, 0, 0, 0);
    }

    const int nc = ct * 32 + n31;           // output col in [0, 2COUT)
    const float bias = (ct < COUT / 32) ? b1[nc] : 0.f;   // A-tile test is wave-uniform
#pragma unroll
    for (int r = 0; r < 16; ++r) {
        const int pt = p0 + (r & 3) + 8 * (r >> 2) + 4 * lh;
        AB[(size_t)pt * N2 + nc] = acc[r] + bias;
    }
}

// sorted ascending top-6 insert via pure min/max network (2 VALU / level).
__device__ __forceinline__ void insert6f(float s, float* dl) {
#pragma unroll
    for (int k = 0; k < 6; ++k) {
        const float a = dl[k];
        dl[k] = fminf(s, a);
        s = fmaxf(s, a);
    }
}

// ---------------- MFMA kNN scan (32x32 tiles, LDS-staged candidates; verified R15) ----------------
// 4-way candidate split, 1024 blocks = 4 blocks/CU, VGPR 48 no-spill.
// R16's 8-way attempt spilled (VGPR forced to 40, 54MB scratch) -- the
// 4-blocks/CU shape is this design's proven operating point.
template<int C>
__global__ __launch_bounds__(256, 4)
void knn_scan(const unsigned short* __restrict__ Xhi,
              const unsigned short* __restrict__ Xlo,
              const float* __restrict__ sqv,
              unsigned* __restrict__ plist) {
    constexpr int KT    = C / 16;           // K=16 tiles per product
    constexpr int SR    = C / 4;            // 16B slots per LDS row (hi+lo)
    constexpr int ROWB  = SR * 16;          // 128 / 256 bytes per row
    constexpr int STEPB = 32 * ROWB;        // 4 KB / 8 KB per step buffer
    constexpr int LPT   = STEPB / 16 / 256; // 1 / 2 loads per thread per step
    __shared__ __align__(16) char sm[2 * STEPB];

    const int tid  = threadIdx.x;
    const int w    = __builtin_amdgcn_readfirstlane(tid >> 6);
    const int bid  = blockIdx.x;
    const int swz  = ((bid & 7) << 7) | (bid >> 3);   // 1024 blocks, 128/XCD
    const int b    = swz >> 6;              // batch (2 per XCD)
    const int sp   = (swz >> 4) & 3;        // candidate quarter
    const int qg   = swz & 15;              // query group of 4 tiles
    const int qt   = qg * 4 + w;            // this wave's query tile (32 q)
    const int lane = tid & 63;
    const int q31  = lane & 31;
    const int lh   = lane >> 5;
    const int base = b * NN;
    const int qloc = qt * 32 + q31;         // batch-local query index

    // persistent query fragments
    short8 bh[KT], bl[KT];
#pragma unroll
    for (int kt = 0; kt < KT; ++kt) {
        const size_t off = (size_t)(base + qloc) * C + kt * 16 + lh * 8;
        bh[kt] = *(const short8*)(Xhi + off);
        bl[kt] = *(const short8*)(Xlo + off);
    }

    float dl[6];
#pragma unroll
    for (int k = 0; k < 6; ++k) dl[k] = 1e30f;

    const int jbeg   = sp * (NN / 4);
    const int selfjb = qt * 32;             // only step that can contain self

    // staging source pointers: thread's LDS slot sidx -> (row, slot);
    // content = SRC[row][slot ^ (row&(SR-1))] (XOR involution; reader undoes it)
    const unsigned short* src[LPT];
#pragma unroll
    for (int l = 0; l < LPT; ++l) {
        const int sidx = tid + l * 256;
        const int row  = sidx / SR;
        const int slot = sidx % SR;
        const int u    = slot ^ (row & (SR - 1));
        const unsigned short* bp = (u < SR / 2) ? Xhi : Xlo;
        src[l] = bp + (size_t)(base + jbeg + row) * C + (u & (SR / 2 - 1)) * 8;
    }

    // per-lane ds-read constants
    const int m       = q31 & (SR - 1);
    const int rowbase = q31 * ROWB;
    const float* sqp  = sqv + base + jbeg + lh * 4;
    float4 s4[4];

#define STAGE(BUF) do {                                                        \
    _Pragma("unroll")                                                          \
    for (int l = 0; l < LPT; ++l) {                                            \
        __builtin_amdgcn_global_load_lds(                                      \
            (const __attribute__((address_space(1))) void*)src[l],             \
            (__attribute__((address_space(3))) void*)                          \
                (sm + (BUF) * STEPB + l * 4096 + w * 1024),                    \
            16, 0, 0);                                                         \
        src[l] += 32 * C;                                                      \
    }                                                                          \
} while (0)

#define COMPUTE(BUF, JB) do {                                                  \
    const char* smc = sm + (BUF) * STEPB;                                      \
    f32x16 acc = {0.f};                                                        \
    _Pragma("unroll")                                                          \
    for (int kt = 0; kt < KT; ++kt) {                                          \
        const int uh = kt * 2 + lh;                                            \
        const int ul = 2 * KT + kt * 2 + lh;                                   \
        const short8 ah = *(const short8*)(smc + rowbase + ((uh ^ m) << 4));   \
        const short8 al = *(const short8*)(smc + rowbase + ((ul ^ m) << 4));   \
        acc = __builtin_amdgcn_mfma_f32_32x32x16_bf16(ah, bh[kt], acc, 0, 0, 0); \
        acc = __builtin_amdgcn_mfma_f32_32x32x16_bf16(ah, bl[kt], acc, 0, 0, 0); \
        acc = __builtin_amdgcn_mfma_f32_32x32x16_bf16(al, bh[kt], acc, 0, 0, 0); \
    }                                                                          \
    const unsigned ebase = (unsigned)(((JB) - jbeg) >> 1);   /* step*16 */     \
    const bool selfstep = ((JB) == selfjb);                                    \
    _Pragma("unroll")                                                          \
    for (int g4 = 0; g4 < 4; ++g4) {                                           \
        _Pragma("unroll")                                                      \
        for (int rr = 0; rr < 4; ++rr) {                                       \
            const int r = g4 * 4 + rr;                                         \
            float sc = fmaf(-2.f, acc[r],                                      \
                rr == 0 ? s4[g4].x : rr == 1 ? s4[g4].y :                      \
                rr == 2 ? s4[g4].z : s4[g4].w);                                \
            sc = __uint_as_float((__float_as_uint(sc) & 0xFFFFFF00u) |         \
                                 (ebase + (unsigned)((r & 3) + 4 * (r >> 2)))); \
            if (selfstep) {                                                    \
                const int rowr = (r & 3) + 8 * (r >> 2) + 4 * lh;              \
                sc = (rowr == q31) ? 1e30f : sc;                               \
            }                                                                  \
            insert6f(sc, dl);                                                  \
        }                                                                      \
    }                                                                          \
} while (0)

    STAGE(0);                               // prologue: step 0 in flight
    int jb = jbeg, cur = 0;
#pragma unroll 1
    for (int st = 0; st < 15; ++st) {
        __builtin_amdgcn_s_barrier();       // WAR: all waves done reading buf cur^1
#pragma unroll
        for (int g4 = 0; g4 < 4; ++g4) s4[g4] = *(const float4*)(sqp + g4 * 8);
        asm volatile("" ::: "memory");      // pin: sq loads issue BEFORE stage
        STAGE(cur ^ 1);                     // step st+1 in flight
        if constexpr (C == 32) asm volatile("s_waitcnt vmcnt(1)" ::: "memory");
        else                   asm volatile("s_waitcnt vmcnt(2)" ::: "memory");
        __builtin_amdgcn_s_barrier();       // RAW: all waves' step-st data landed
        COMPUTE(cur, jb);
        jb += 32; sqp += 32; cur ^= 1;
    }
    {   // epilogue: last step, drain
        __builtin_amdgcn_s_barrier();
#pragma unroll
        for (int g4 = 0; g4 < 4; ++g4) s4[g4] = *(const float4*)(sqp + g4 * 8);
        asm volatile("s_waitcnt vmcnt(0)" ::: "memory");
        __builtin_amdgcn_s_barrier();
        COMPUTE(cur, jb);
    }
#undef STAGE
#undef COMPUTE

    // write this lane's sorted sublist as sortable-transformed u32 keys
    unsigned* o = plist + (size_t)(base + qloc) * 48 + (sp * 2 + lh) * 6;
#pragma unroll
    for (int k = 0; k < 6; ++k) {
        const unsigned bits = __float_as_uint(dl[k]);
        o[k] = bits ^ ((bits & 0x80000000u) ? 0xFFFFFFFFu : 0x80000000u);
    }
}

// ---------------- exact rescore: 2 threads/query (verified R11/R15) ----------------
template<int C>
__global__ __launch_bounds__(256)
void rescore(const float* __restrict__ x, const float* __restrict__ sqv,
             const unsigned* __restrict__ plist, int* __restrict__ nbr) {
    const int bid  = blockIdx.x;
    const int bsw  = ((bid & 7) << 5) | (bid >> 3);   // 256 blocks, bijective
    const int gi   = bsw * 256 + threadIdx.x;
    const int i    = gi >> 1;
    const int slot = gi & 1;

    const unsigned* pr = plist + (size_t)i * 48 + slot * 24;

    unsigned long long best[7];
#pragma unroll
    for (int k = 0; k < 7; ++k) best[k] = ~0ull;
    for (int z4 = 0; z4 < 4; ++z4) {
        const unsigned* p = pr + z4 * 6;
        const unsigned zg = (unsigned)(slot * 4 + z4);
        for (int e = 0; e < 6; ++e) {
            unsigned long long v = ((unsigned long long)p[e] << 3) | zg;
            if (v >= best[6]) break;      // sublist ascending
            best[6] = v;
#pragma unroll
            for (int k = 5; k >= 0; --k) {
                if (best[k + 1] < best[k]) {
                    unsigned long long t = best[k]; best[k] = best[k + 1]; best[k + 1] = t;
                }
            }
        }
    }

    const int base = i & ~(NN - 1);
    float4 qv[C / 4];
    const float4* qp = (const float4*)(x + (size_t)i * C);
#pragma unroll
    for (int t = 0; t < C / 4; ++t) qv[t] = qp[t];

    unsigned long long out6[6];
#pragma unroll
    for (int k = 0; k < 6; ++k) out6[k] = ~0ull;

    for (int m = 0; m < 7; ++m) {
        const unsigned u32k = (unsigned)(best[m] >> 3);
        const int z = (int)(best[m] & 7ull);
        const unsigned orig = (u32k & 0x80000000u) ? (u32k ^ 0x80000000u) : ~u32k;
        const int e = (int)(orig & 255u);
        const int idx = e & 15;
        const int jloc = (z >> 1) * (NN / 4) + (e >> 4) * 32 +
                         (idx & 3) + 8 * (idx >> 2) + (z & 1) * 4;

        const float4* cp = (const float4*)(x + (size_t)(base + jloc) * C);
        float d0 = 0.f, d1 = 0.f, d2 = 0.f, d3 = 0.f;
#pragma unroll
        for (int t = 0; t < C / 4; ++t) {
            float4 a = cp[t];
            d0 = fmaf(a.x, qv[t].x, d0);
            d1 = fmaf(a.y, qv[t].y, d1);
            d2 = fmaf(a.z, qv[t].z, d2);
            d3 = fmaf(a.w, qv[t].w, d3);
        }
        const float s = fmaf(-2.f, (d0 + d1) + (d2 + d3), sqv[base + jloc]);
        unsigned u = __float_as_uint(s);
        u ^= (u & 0x80000000u) ? 0xFFFFFFFFu : 0x80000000u;
        unsigned long long key = ((unsigned long long)u << 11) | (unsigned)jloc;
#pragma unroll
        for (int k = 0; k < 6; ++k) {
            const unsigned long long ok = out6[k];
            const bool c = key < ok;
            out6[k] = c ? key : ok;
            key     = c ? ok  : key;
        }
    }

    // exchange per-half exact top-6 with partner; merge to final top-6
    unsigned long long fin[6];
#pragma unroll
    for (int k = 0; k < 6; ++k) fin[k] = out6[k];
#pragma unroll
    for (int k = 0; k < 6; ++k) {
        const unsigned long long v = out6[k];
        const unsigned lo = __shfl_xor((unsigned)v, 1);
        const unsigned hi = __shfl_xor((unsigned)(v >> 32), 1);
        unsigned long long key = ((unsigned long long)hi << 32) | lo;
#pragma unroll
        for (int q = 0; q < 6; ++q) {
            const unsigned long long ok = fin[q];
            const bool c = key < ok;
            fin[q] = c ? key : ok;
            key    = c ? ok  : key;
        }
    }
#pragma unroll
    for (int k = 0; k < 3; ++k)
        nbr[i * KNB + slot * 3 + k] = base + (int)(fin[slot * 3 + k] & 2047ull);
}

// ---------------- edge MLP kernel (gathered A/B from the MFMA-computed AB; verified R15) ----------------
template<int COUT, bool RESID, int MINW>
__global__ __launch_bounds__(768, MINW)
void mlp_kernel(const float* __restrict__ AB, const int* __restrict__ nbr,
                const float* __restrict__ W2, const float* __restrict__ b2,
                const float* __restrict__ resid, float* __restrict__ out) {
    constexpr int HALF = COUT / 2;
    constexpr int NQ   = COUT / 4;
    constexpr int N2   = 2 * COUT;
    constexpr int RS = HALF + 4;
    __shared__ float Buf[2][3][64][RS];

    const int tid  = threadIdx.x;
    const int lane = tid & 63;
    const int wv   = __builtin_amdgcn_readfirstlane(tid >> 6);  // 0..11
    const int oh   = wv / 6;                                    // output half
    const int w6   = wv % 6;                                    // neighbor
    const int bid  = blockIdx.x;
    const int bsw  = ((bid & 7) << 6) | (bid >> 3);             // XCD swizzle, 512 blocks
    const int i    = bsw * 64 + lane;
    const int j    = nbr[i * KNB + w6];

    f32x2 uacc[HALF / 2];
#pragma unroll
    for (int o = 0; o < HALF / 2; ++o) uacc[o] = (f32x2){0.f, 0.f};

    cfloat* W2c = (cfloat*)(uintptr_t)W2;
    const float* Ap = AB + (size_t)i * N2;
    const float* Bp = AB + (size_t)j * N2 + COUT;

    const int qofs = (wv * 3) & (NQ - 1);    // wave-staggered op start

#pragma unroll 2
    for (int qi = 0; qi < NQ; ++qi) {
        const int oq = (qi + qofs) & (NQ - 1);
        const float4 a4 = *(const float4*)(Ap + 4 * oq);
        const float4 b4 = *(const float4*)(Bp + 4 * oq);
#pragma unroll
        for (int rr = 0; rr < 4; ++rr) {
            const int op = oq * 4 + rr;
            const float aop = rr == 0 ? a4.x : rr == 1 ? a4.y : rr == 2 ? a4.z : a4.w;
            const float bop = rr == 0 ? b4.x : rr == 1 ? b4.y : rr == 2 ? b4.z : b4.w;
            const float h = fmaxf(aop + bop, 0.f);
            cf32x2* w2p = (cf32x2*)(W2c + (size_t)op * COUT + oh * HALF);
            const f32x2 hv = {h, h};
#pragma unroll
            for (int o = 0; o < HALF / 2; ++o)
                uacc[o] += w2p[o] * hv;          // v_pk_fma_f32
        }
    }

    // per-half 6 -> 1 max tree over neighbor waves
    if (w6 >= 3) {
#pragma unroll
        for (int o = 0; o < HALF / 2; ++o) {
            Buf[oh][w6 - 3][lane][2 * o]     = uacc[o].x;
            Buf[oh][w6 - 3][lane][2 * o + 1] = uacc[o].y;
        }
    }
    __syncthreads();
    if (w6 < 3) {
#pragma unroll
        for (int o = 0; o < HALF / 2; ++o) {
            uacc[o].x = fmaxf(uacc[o].x, Buf[oh][w6][lane][2 * o]);
            uacc[o].y = fmaxf(uacc[o].y, Buf[oh][w6][lane][2 * o + 1]);
        }
    }
    __syncthreads();
    if (w6 == 1 || w6 == 2) {
#pragma unroll
        for (int o = 0; o < HALF / 2; ++o) {
            Buf[oh][w6][lane][2 * o]     = uacc[o].x;
            Buf[oh][w6][lane][2 * o + 1] = uacc[o].y;
        }
    }
    __syncthreads();
    if (w6 == 0) {
        float* po = out + (size_t)i * COUT + oh * HALF;
        const float* b2p = b2 + oh * HALF;
        const float* rp  = RESID ? (resid + (size_t)i * COUT + oh * HALF) : nullptr;
#pragma unroll
        for (int o = 0; o < HALF / 2; ++o) {
            float v0 = fmaxf(uacc[o].x,
                             fmaxf(Buf[oh][1][lane][2 * o], Buf[oh][2][lane][2 * o])) + b2p[2 * o];
            float v1 = fmaxf(uacc[o].y,
                             fmaxf(Buf[oh][1][lane][2 * o + 1], Buf[oh][2][lane][2 * o + 1])) + b2p[2 * o + 1];
            if (RESID) { v0 += rp[2 * o]; v1 += rp[2 * o + 1]; }
            po[2 * o]     = fmaxf(v0, 0.f);
            po[2 * o + 1] = fmaxf(v1, 0.f);
        }
    }
}

extern "C" void kernel_launch(void* const* d_in, const int* in_sizes, int n_in,
                              void* d_out, int out_size, void* d_ws, size_t ws_size,
                              hipStream_t stream) {
    const float* x    = (const float*)d_in[0];
    const float* W1_0 = (const float*)d_in[2];
    const float* b1_0 = (const float*)d_in[3];
    const float* W2_0 = (const float*)d_in[4];
    const float* b2_0 = (const float*)d_in[5];
    const float* W1_1 = (const float*)d_in[6];
    const float* b1_1 = (const float*)d_in[7];
    const float* W2_1 = (const float*)d_in[8];
    const float* b2_1 = (const float*)d_in[9];
    const float* W1_2 = (const float*)d_in[10];
    const float* b1_2 = (const float*)d_in[11];
    const float* W2_2 = (const float*)d_in[12];
    const float* b2_2 = (const float*)d_in[13];
    float* outp = (float*)d_out;

    // workspace layout
    unsigned* plist = (unsigned*)d_ws;                            // NPTS*48 u32
    float* x0  = (float*)(plist + (size_t)NPTS * 48);             // 32768 x 64
    float* x1  = x0 + (size_t)NPTS * 64;                          // 32768 x 32
    float* sqb = x1 + (size_t)NPTS * 32;                          // 32768
    unsigned short* Whi0 = (unsigned short*)(sqb + NPTS);         // 6 x 4096 u16
    unsigned short* Wlo0 = Whi0 + 4096;
    unsigned short* Whi1 = Wlo0 + 4096;
    unsigned short* Wlo1 = Whi1 + 4096;
    unsigned short* Whi2 = Wlo1 + 4096;
    unsigned short* Wlo2 = Whi2 + 4096;
    unsigned short* Xhi = Wlo2 + 4096;                            // 32768 x 64 u16
    unsigned short* Xlo = Xhi + (size_t)NPTS * 64;                // 32768 x 64 u16
    int* nbr = (int*)(Xlo + (size_t)NPTS * 64);                   // 32768 x 6
    float* AB = (float*)(nbr + (size_t)NPTS * KNB);               // 32768 x 128

    const int fgrid  = NPTS / 64;       // prep_split: 4 thr/point, 512 blocks
    const int rgrid  = NPTS * 2 / 256;  // rescore: 2 thr/query, 256 blocks
    const int scgrid = 1024;            // 4096 waves of 32q x 512c
    const int pgrid  = NPTS / 64;       // 512 blocks x 768 thr

    prep_w<<<16, 256, 0, stream>>>(W1_0, W1_1, W1_2, Whi0, Wlo0, Whi1, Wlo1, Whi2, Wlo2);

    // ---- layer 0: x (32) -> x0 (64), relu ----
    prep_split<32><<<fgrid, 256, 0, stream>>>(x, Xhi, Xlo, sqb);
    ab_gemm<32, 64><<<NPTS / 32, 256, 0, stream>>>(Xhi, Xlo, Whi0, Wlo0, b1_0, AB);
    knn_scan<32><<<scgrid, 256, 0, stream>>>(Xhi, Xlo, sqb, plist);
    rescore<32><<<rgrid, 256, 0, stream>>>(x, sqb, plist, nbr);
    mlp_kernel<64, false, 5><<<pgrid, 768, 0, stream>>>(AB, nbr, W2_0, b2_0, nullptr, x0);

    // ---- layer 1: x0 (64) -> x1 (32), relu ----
    prep_split<64><<<fgrid, 256, 0, stream>>>(x0, Xhi, Xlo, sqb);
    ab_gemm<64, 32><<<NPTS / 64, 256, 0, stream>>>(Xhi, Xlo, Whi1, Wlo1, b1_1, AB);
    knn_scan<64><<<scgrid, 256, 0, stream>>>(Xhi, Xlo, sqb, plist);
    rescore<64><<<rgrid, 256, 0, stream>>>(x0, sqb, plist, nbr);
    mlp_kernel<32, false, 4><<<pgrid, 768, 0, stream>>>(AB, nbr, W2_1, b2_1, nullptr, x1);

    // ---- layer 2: x1 (32) -> out (64), +x0 residual, relu ----
    prep_split<32><<<fgrid, 256, 0, stream>>>(x1, Xhi, Xlo, sqb);
    ab_gemm<32, 64><<<NPTS / 32, 256, 0, stream>>>(Xhi, Xlo, Whi2, Wlo2, b1_2, AB);
    knn_scan<32><<<scgrid, 256, 0, stream>>>(Xhi, Xlo, sqb, plist);
    rescore<32><<<rgrid, 256, 0, stream>>>(x1, sqb, plist, nbr);
    mlp_kernel<64, true, 5><<<pgrid, 768, 0, stream>>>(AB, nbr, W2_2, b2_2, x0, outp);
}

// Round 18
// 405.133 us; speedup vs baseline: 1.1102x; 1.0033x over previous
//
#include <hip/hip_runtime.h>

#define NB   16
#define NN   2048
#define NPTS (NB * NN)
#define KNB  6

typedef __attribute__((ext_vector_type(8))) short short8;
typedef __attribute__((ext_vector_type(2))) float f32x2;
typedef __attribute__((ext_vector_type(4))) float f32x4;
typedef __attribute__((ext_vector_type(16))) float f32x16;
typedef const __attribute__((address_space(4))) float cfloat;
typedef const __attribute__((address_space(4))) f32x2 cf32x2;

__device__ __forceinline__ unsigned bf16_rne(float f) {
    unsigned u = __float_as_uint(f);
    return (u + 0x7fffu + ((u >> 16) & 1u)) >> 16;
}

// ---------------- prep: bf16 hi/lo split + |x|^2 ONLY (verified R15) ----------------
template<int C>
__global__ __launch_bounds__(256)
void prep_split(const float* __restrict__ x,
                unsigned short* __restrict__ Xhi,
                unsigned short* __restrict__ Xlo,
                float* __restrict__ sq) {
    const int tid  = threadIdx.x;
    const int slot = tid & 3;
    const int i    = blockIdx.x * 64 + (tid >> 2);
    constexpr int Q = C / 4;

    float r[Q];
    const float4* rp = (const float4*)(x + (size_t)i * C + slot * Q);
#pragma unroll
    for (int c4 = 0; c4 < Q / 4; ++c4) {
        float4 f = rp[c4];
        r[4 * c4] = f.x; r[4 * c4 + 1] = f.y; r[4 * c4 + 2] = f.z; r[4 * c4 + 3] = f.w;
    }
    float s = 0.f;
#pragma unroll
    for (int c = 0; c < Q; ++c) s = fmaf(r[c], r[c], s);
    s += __shfl_xor(s, 1);
    s += __shfl_xor(s, 2);
    if (slot == 0) sq[i] = s;

#pragma unroll
    for (int cc = 0; cc < Q; cc += 8) {
        short8 vh, vl;
#pragma unroll
        for (int t = 0; t < 8; ++t) {
            const float f = r[cc + t];
            const unsigned h = bf16_rne(f);
            const float hf = __uint_as_float(h << 16);
            vh[t] = (short)h;
            vl[t] = (short)bf16_rne(f - hf);
        }
        *(short8*)(Xhi + (size_t)i * C + slot * Q + cc) = vh;
        *(short8*)(Xlo + (size_t)i * C + slot * Q + cc) = vl;
    }
}

// ---------------- weight prep: bf16 hi/lo of combined [2COUT][C] GEMM weights (verified R15) ----------------
__global__ void prep_w(const float* __restrict__ W10, const float* __restrict__ W11,
                       const float* __restrict__ W12,
                       unsigned short* __restrict__ Whi0, unsigned short* __restrict__ Wlo0,
                       unsigned short* __restrict__ Whi1, unsigned short* __restrict__ Wlo1,
                       unsigned short* __restrict__ Whi2, unsigned short* __restrict__ Wlo2) {
    int t = blockIdx.x * 256 + threadIdx.x;
    if (t >= 4096) return;
    {   // L0 / L2: n = t>>5 in [0,128), k = t&31
        const int n = t >> 5, k = t & 31;
        float v0, v2;
        if (n < 64) { v0 = W10[k * 64 + n] - W10[(32 + k) * 64 + n];
                      v2 = W12[k * 64 + n] - W12[(32 + k) * 64 + n]; }
        else        { v0 = W10[(32 + k) * 64 + (n - 64)];
                      v2 = W12[(32 + k) * 64 + (n - 64)]; }
        unsigned h0 = bf16_rne(v0);
        Whi0[t] = (unsigned short)h0;
        Wlo0[t] = (unsigned short)bf16_rne(v0 - __uint_as_float(h0 << 16));
        unsigned h2 = bf16_rne(v2);
        Whi2[t] = (unsigned short)h2;
        Wlo2[t] = (unsigned short)bf16_rne(v2 - __uint_as_float(h2 << 16));
    }
    {   // L1: n = t>>6 in [0,64), k = t&63
        const int n = t >> 6, k = t & 63;
        float v;
        if (n < 32) v = W11[k * 32 + n] - W11[(64 + k) * 32 + n];
        else        v = W11[(64 + k) * 32 + (n - 32)];
        unsigned h = bf16_rne(v);
        Whi1[t] = (unsigned short)h;
        Wlo1[t] = (unsigned short)bf16_rne(v - __uint_as_float(h << 16));
    }
}

// ---------------- AB GEMM (verified R15) ----------------
template<int C, int COUT>
__global__ __launch_bounds__(256, 2)
void ab_gemm(const unsigned short* __restrict__ Xhi,
             const unsigned short* __restrict__ Xlo,
             const unsigned short* __restrict__ Whi,
             const unsigned short* __restrict__ Wlo,
             const float* __restrict__ b1, float* __restrict__ AB) {
    constexpr int KT  = C / 16;
    constexpr int N2  = 2 * COUT;
    constexpr int NCT = N2 / 32;            // col tiles: 4 (L0/2), 2 (L1)
    constexpr int RPB = 4 / NCT;            // row tiles per block
    const int w    = __builtin_amdgcn_readfirstlane(threadIdx.x >> 6);
    const int lane = threadIdx.x & 63;
    const int n31  = lane & 31;
    const int lh   = lane >> 5;
    const int rt   = blockIdx.x * RPB + w / NCT;
    const int ct   = w % NCT;
    const int p0   = rt * 32;

    short8 ah[KT], al[KT], wh[KT], wl[KT];
#pragma unroll
    for (int kt = 0; kt < KT; ++kt) {
        const size_t poff = (size_t)(p0 + n31) * C + kt * 16 + lh * 8;
        ah[kt] = *(const short8*)(Xhi + poff);
        al[kt] = *(const short8*)(Xlo + poff);
        const size_t woff = (size_t)(ct * 32 + n31) * C + kt * 16 + lh * 8;
        wh[kt] = *(const short8*)(Whi + woff);
        wl[kt] = *(const short8*)(Wlo + woff);
    }

    f32x16 acc = {0.f};
#pragma unroll
    for (int kt = 0; kt < KT; ++kt) {
        acc = __builtin_amdgcn_mfma_f32_32x32x16_bf16(ah[kt], wh[kt], acc, 0, 0, 0);
        acc = __builtin_amdgcn_mfma_f32_32x32x16_bf16(ah[kt], wl[kt], acc, 0, 0, 0);
        acc = __builtin_amdgcn_mfma_f32_32x32x16_bf16(al[kt], wh[kt], acc, 0, 0, 0);
    }

    const int nc = ct * 32 + n31;           // output col in [0, 2COUT)
    const float bias = (ct < COUT / 32) ? b1[nc] : 0.f;   // A-tile test is wave-uniform
#pragma unroll
    for (int r = 0; r < 16; ++r) {
        const int pt = p0 + (r & 3) + 8 * (r >> 2) + 4 * lh;
        AB[(size_t)pt * N2 + nc] = acc[r] + bias;
    }
}

// sorted ascending top-6 insert via pure min/max network (2 VALU / level).
__device__ __forceinline__ void insert6f(float s, float* dl) {
#pragma unroll
    for (int k = 0; k < 6; ++k) {
        const float a = dl[k];
        dl[k] = fminf(s, a);
        s = fmaxf(s, a);
    }
}

// ---------------- MFMA kNN scan (32x32 tiles, TRIPLE-buffered LDS staging) ----------------
// R17 PMC: VALU 57 + MFMA 19 = 76% issue, ~24% idle from 2 s_barriers per
// 32-cand step (32 barriers/scan; all 16 waves convoy on the stage drain).
// Triple buffering makes one barrier per step sufficient: staging at iter st
// targets the buffer last read at st-2; barrier-bounded skew (<=1 segment)
// means no wave can still be reading it (checked for skew +-1). Per iter:
// {s4 loads; STAGE(next); vmcnt(LPT+4) [drains own previous stage: ops newer
// than it = 4 sq + LPT stage]; s_barrier; COMPUTE(cur)}. Barriers 32 -> 16.
// LDS 3xSTEPB = 12/24 KB -> 48/96 KB per CU at 4 blocks/CU (<=160).
// Everything else identical to the verified R15/R17 kernel.
template<int C>
__global__ __launch_bounds__(256, 4)
void knn_scan(const unsigned short* __restrict__ Xhi,
              const unsigned short* __restrict__ Xlo,
              const float* __restrict__ sqv,
              unsigned* __restrict__ plist) {
    constexpr int KT    = C / 16;           // K=16 tiles per product
    constexpr int SR    = C / 4;            // 16B slots per LDS row (hi+lo)
    constexpr int ROWB  = SR * 16;          // 128 / 256 bytes per row
    constexpr int STEPB = 32 * ROWB;        // 4 KB / 8 KB per step buffer
    constexpr int LPT   = STEPB / 16 / 256; // 1 / 2 loads per thread per step
    __shared__ __align__(16) char sm[3 * STEPB];

    const int tid  = threadIdx.x;
    const int w    = __builtin_amdgcn_readfirstlane(tid >> 6);
    const int bid  = blockIdx.x;
    const int swz  = ((bid & 7) << 7) | (bid >> 3);   // 1024 blocks, 128/XCD
    const int b    = swz >> 6;              // batch (2 per XCD)
    const int sp   = (swz >> 4) & 3;        // candidate quarter
    const int qg   = swz & 15;              // query group of 4 tiles
    const int qt   = qg * 4 + w;            // this wave's query tile (32 q)
    const int lane = tid & 63;
    const int q31  = lane & 31;
    const int lh   = lane >> 5;
    const int base = b * NN;
    const int qloc = qt * 32 + q31;         // batch-local query index

    // persistent query fragments
    short8 bh[KT], bl[KT];
#pragma unroll
    for (int kt = 0; kt < KT; ++kt) {
        const size_t off = (size_t)(base + qloc) * C + kt * 16 + lh * 8;
        bh[kt] = *(const short8*)(Xhi + off);
        bl[kt] = *(const short8*)(Xlo + off);
    }

    float dl[6];
#pragma unroll
    for (int k = 0; k < 6; ++k) dl[k] = 1e30f;

    const int jbeg   = sp * (NN / 4);
    const int selfjb = qt * 32;             // only step that can contain self

    // staging source pointers: thread's LDS slot sidx -> (row, slot);
    // content = SRC[row][slot ^ (row&(SR-1))] (XOR involution; reader undoes it)
    const unsigned short* src[LPT];
#pragma unroll
    for (int l = 0; l < LPT; ++l) {
        const int sidx = tid + l * 256;
        const int row  = sidx / SR;
        const int slot = sidx % SR;
        const int u    = slot ^ (row & (SR - 1));
        const unsigned short* bp = (u < SR / 2) ? Xhi : Xlo;
        src[l] = bp + (size_t)(base + jbeg + row) * C + (u & (SR / 2 - 1)) * 8;
    }

    // per-lane ds-read constants
    const int m       = q31 & (SR - 1);
    const int rowbase = q31 * ROWB;
    const float* sqp  = sqv + base + jbeg + lh * 4;
    float4 s4[4];

#define STAGE(BUF) do {                                                        \
    _Pragma("unroll")                                                          \
    for (int l = 0; l < LPT; ++l) {                                            \
        __builtin_amdgcn_global_load_lds(                                      \
            (const __attribute__((address_space(1))) void*)src[l],             \
            (__attribute__((address_space(3))) void*)                          \
                (sm + (BUF) * STEPB + l * 4096 + w * 1024),                    \
            16, 0, 0);                                                         \
        src[l] += 32 * C;                                                      \
    }                                                                          \
} while (0)

#define COMPUTE(BUF, JB) do {                                                  \
    const char* smc = sm + (BUF) * STEPB;                                      \
    f32x16 acc = {0.f};                                                        \
    _Pragma("unroll")                                                          \
    for (int kt = 0; kt < KT; ++kt) {                                          \
        const int uh = kt * 2 + lh;                                            \
        const int ul = 2 * KT + kt * 2 + lh;                                   \
        const short8 ah = *(const short8*)(smc + rowbase + ((uh ^ m) << 4));   \
        const short8 al = *(const short8*)(smc + rowbase + ((ul ^ m) << 4));   \
        acc = __builtin_amdgcn_mfma_f32_32x32x16_bf16(ah, bh[kt], acc, 0, 0, 0); \
        acc = __builtin_amdgcn_mfma_f32_32x32x16_bf16(ah, bl[kt], acc, 0, 0, 0); \
        acc = __builtin_amdgcn_mfma_f32_32x32x16_bf16(al, bh[kt], acc, 0, 0, 0); \
    }                                                                          \
    const unsigned ebase = (unsigned)(((JB) - jbeg) >> 1);   /* step*16 */     \
    const bool selfstep = ((JB) == selfjb);                                    \
    _Pragma("unroll")                                                          \
    for (int g4 = 0; g4 < 4; ++g4) {                                           \
        _Pragma("unroll")                                                      \
        for (int rr = 0; rr < 4; ++rr) {                                       \
            const int r = g4 * 4 + rr;                                         \
            float sc = fmaf(-2.f, acc[r],                                      \
                rr == 0 ? s4[g4].x : rr == 1 ? s4[g4].y :                      \
                rr == 2 ? s4[g4].z : s4[g4].w);                                \
            sc = __uint_as_float((__float_as_uint(sc) & 0xFFFFFF00u) |         \
                                 (ebase + (unsigned)((r & 3) + 4 * (r >> 2)))); \
            if (selfstep) {                                                    \
                const int rowr = (r & 3) + 8 * (r >> 2) + 4 * lh;              \
                sc = (rowr == q31) ? 1e30f : sc;                               \
            }                                                                  \
            insert6f(sc, dl);                                                  \
        }                                                                      \
    }                                                                          \
} while (0)

    STAGE(0);                               // prologue: step 0 in flight
    int jb = jbeg, cur = 0, nxt = 1;
#pragma unroll 1
    for (int st = 0; st < 15; ++st) {
#pragma unroll
        for (int g4 = 0; g4 < 4; ++g4) s4[g4] = *(const float4*)(sqp + g4 * 8);
        asm volatile("" ::: "memory");      // pin: sq loads issue BEFORE stage
        STAGE(nxt);                         // step st+1 in flight
        if constexpr (C == 32) asm volatile("s_waitcnt vmcnt(5)" ::: "memory");
        else                   asm volatile("s_waitcnt vmcnt(6)" ::: "memory");
        __builtin_amdgcn_s_barrier();       // step-st data landed (all waves)
        COMPUTE(cur, jb);
        jb += 32; sqp += 32;
        cur = nxt;
        nxt = (nxt == 2) ? 0 : nxt + 1;
    }
    {   // epilogue: last step, drain
#pragma unroll
        for (int g4 = 0; g4 < 4; ++g4) s4[g4] = *(const float4*)(sqp + g4 * 8);
        asm volatile("s_waitcnt vmcnt(0)" ::: "memory");
        __builtin_amdgcn_s_barrier();
        COMPUTE(cur, jb);
    }
#undef STAGE
#undef COMPUTE

    // write this lane's sorted sublist as sortable-transformed u32 keys
    unsigned* o = plist + (size_t)(base + qloc) * 48 + (sp * 2 + lh) * 6;
#pragma unroll
    for (int k = 0; k < 6; ++k) {
        const unsigned bits = __float_as_uint(dl[k]);
        o[k] = bits ^ ((bits & 0x80000000u) ? 0xFFFFFFFFu : 0x80000000u);
    }
}

// ---------------- exact rescore: 2 threads/query (verified R11/R15) ----------------
template<int C>
__global__ __launch_bounds__(256)
void rescore(const float* __restrict__ x, const float* __restrict__ sqv,
             const unsigned* __restrict__ plist, int* __restrict__ nbr) {
    const int bid  = blockIdx.x;
    const int bsw  = ((bid & 7) << 5) | (bid >> 3);   // 256 blocks, bijective
    const int gi   = bsw * 256 + threadIdx.x;
    const int i    = gi >> 1;
    const int slot = gi & 1;

    const unsigned* pr = plist + (size_t)i * 48 + slot * 24;

    unsigned long long best[7];
#pragma unroll
    for (int k = 0; k < 7; ++k) best[k] = ~0ull;
    for (int z4 = 0; z4 < 4; ++z4) {
        const unsigned* p = pr + z4 * 6;
        const unsigned zg = (unsigned)(slot * 4 + z4);
        for (int e = 0; e < 6; ++e) {
            unsigned long long v = ((unsigned long long)p[e] << 3) | zg;
            if (v >= best[6]) break;      // sublist ascending
            best[6] = v;
#pragma unroll
            for (int k = 5; k >= 0; --k) {
                if (best[k + 1] < best[k]) {
                    unsigned long long t = best[k]; best[k] = best[k + 1]; best[k + 1] = t;
                }
            }
        }
    }

    const int base = i & ~(NN - 1);
    float4 qv[C / 4];
    const float4* qp = (const float4*)(x + (size_t)i * C);
#pragma unroll
    for (int t = 0; t < C / 4; ++t) qv[t] = qp[t];

    unsigned long long out6[6];
#pragma unroll
    for (int k = 0; k < 6; ++k) out6[k] = ~0ull;

    for (int m = 0; m < 7; ++m) {
        const unsigned u32k = (unsigned)(best[m] >> 3);
        const int z = (int)(best[m] & 7ull);
        const unsigned orig = (u32k & 0x80000000u) ? (u32k ^ 0x80000000u) : ~u32k;
        const int e = (int)(orig & 255u);
        const int idx = e & 15;
        const int jloc = (z >> 1) * (NN / 4) + (e >> 4) * 32 +
                         (idx & 3) + 8 * (idx >> 2) + (z & 1) * 4;

        const float4* cp = (const float4*)(x + (size_t)(base + jloc) * C);
        float d0 = 0.f, d1 = 0.f, d2 = 0.f, d3 = 0.f;
#pragma unroll
        for (int t = 0; t < C / 4; ++t) {
            float4 a = cp[t];
            d0 = fmaf(a.x, qv[t].x, d0);
            d1 = fmaf(a.y, qv[t].y, d1);
            d2 = fmaf(a.z, qv[t].z, d2);
            d3 = fmaf(a.w, qv[t].w, d3);
        }
        const float s = fmaf(-2.f, (d0 + d1) + (d2 + d3), sqv[base + jloc]);
        unsigned u = __float_as_uint(s);
        u ^= (u & 0x80000000u) ? 0xFFFFFFFFu : 0x80000000u;
        unsigned long long key = ((unsigned long long)u << 11) | (unsigned)jloc;
#pragma unroll
        for (int k = 0; k < 6; ++k) {
            const unsigned long long ok = out6[k];
            const bool c = key < ok;
            out6[k] = c ? key : ok;
            key     = c ? ok  : key;
        }
    }

    // exchange per-half exact top-6 with partner; merge to final top-6
    unsigned long long fin[6];
#pragma unroll
    for (int k = 0; k < 6; ++k) fin[k] = out6[k];
#pragma unroll
    for (int k = 0; k < 6; ++k) {
        const unsigned long long v = out6[k];
        const unsigned lo = __shfl_xor((unsigned)v, 1);
        const unsigned hi = __shfl_xor((unsigned)(v >> 32), 1);
        unsigned long long key = ((unsigned long long)hi << 32) | lo;
#pragma unroll
        for (int q = 0; q < 6; ++q) {
            const unsigned long long ok = fin[q];
            const bool c = key < ok;
            fin[q] = c ? key : ok;
            key    = c ? ok  : key;
        }
    }
#pragma unroll
    for (int k = 0; k < 3; ++k)
        nbr[i * KNB + slot * 3 + k] = base + (int)(fin[slot * 3 + k] & 2047ull);
}

// ---------------- edge MLP kernel (gathered A/B from the MFMA-computed AB; verified R15) ----------------
template<int COUT, bool RESID, int MINW>
__global__ __launch_bounds__(768, MINW)
void mlp_kernel(const float* __restrict__ AB, const int* __restrict__ nbr,
                const float* __restrict__ W2, const float* __restrict__ b2,
                const float* __restrict__ resid, float* __restrict__ out) {
    constexpr int HALF = COUT / 2;
    constexpr int NQ   = COUT / 4;
    constexpr int N2   = 2 * COUT;
    constexpr int RS = HALF + 4;
    __shared__ float Buf[2][3][64][RS];

    const int tid  = threadIdx.x;
    const int lane = tid & 63;
    const int wv   = __builtin_amdgcn_readfirstlane(tid >> 6);  // 0..11
    const int oh   = wv / 6;                                    // output half
    const int w6   = wv % 6;                                    // neighbor
    const int bid  = blockIdx.x;
    const int bsw  = ((bid & 7) << 6) | (bid >> 3);             // XCD swizzle, 512 blocks
    const int i    = bsw * 64 + lane;
    const int j    = nbr[i * KNB + w6];

    f32x2 uacc[HALF / 2];
#pragma unroll
    for (int o = 0; o < HALF / 2; ++o) uacc[o] = (f32x2){0.f, 0.f};

    cfloat* W2c = (cfloat*)(uintptr_t)W2;
    const float* Ap = AB + (size_t)i * N2;
    const float* Bp = AB + (size_t)j * N2 + COUT;

    const int qofs = (wv * 3) & (NQ - 1);    // wave-staggered op start

#pragma unroll 2
    for (int qi = 0; qi < NQ; ++qi) {
        const int oq = (qi + qofs) & (NQ - 1);
        const float4 a4 = *(const float4*)(Ap + 4 * oq);
        const float4 b4 = *(const float4*)(Bp + 4 * oq);
#pragma unroll
        for (int rr = 0; rr < 4; ++rr) {
            const int op = oq * 4 + rr;
            const float aop = rr == 0 ? a4.x : rr == 1 ? a4.y : rr == 2 ? a4.z : a4.w;
            const float bop = rr == 0 ? b4.x : rr == 1 ? b4.y : rr == 2 ? b4.z : b4.w;
            const float h = fmaxf(aop + bop, 0.f);
            cf32x2* w2p = (cf32x2*)(W2c + (size_t)op * COUT + oh * HALF);
            const f32x2 hv = {h, h};
#pragma unroll
            for (int o = 0; o < HALF / 2; ++o)
                uacc[o] += w2p[o] * hv;          // v_pk_fma_f32
        }
    }

    // per-half 6 -> 1 max tree over neighbor waves
    if (w6 >= 3) {
#pragma unroll
        for (int o = 0; o < HALF / 2; ++o) {
            Buf[oh][w6 - 3][lane][2 * o]     = uacc[o].x;
            Buf[oh][w6 - 3][lane][2 * o + 1] = uacc[o].y;
        }
    }
    __syncthreads();
    if (w6 < 3) {
#pragma unroll
        for (int o = 0; o < HALF / 2; ++o) {
            uacc[o].x = fmaxf(uacc[o].x, Buf[oh][w6][lane][2 * o]);
            uacc[o].y = fmaxf(uacc[o].y, Buf[oh][w6][lane][2 * o + 1]);
        }
    }
    __syncthreads();
    if (w6 == 1 || w6 == 2) {
#pragma unroll
        for (int o = 0; o < HALF / 2; ++o) {
            Buf[oh][w6][lane][2 * o]     = uacc[o].x;
            Buf[oh][w6][lane][2 * o + 1] = uacc[o].y;
        }
    }
    __syncthreads();
    if (w6 == 0) {
        float* po = out + (size_t)i * COUT + oh * HALF;
        const float* b2p = b2 + oh * HALF;
        const float* rp  = RESID ? (resid + (size_t)i * COUT + oh * HALF) : nullptr;
#pragma unroll
        for (int o = 0; o < HALF / 2; ++o) {
            float v0 = fmaxf(uacc[o].x,
                             fmaxf(Buf[oh][1][lane][2 * o], Buf[oh][2][lane][2 * o])) + b2p[2 * o];
            float v1 = fmaxf(uacc[o].y,
                             fmaxf(Buf[oh][1][lane][2 * o + 1], Buf[oh][2][lane][2 * o + 1])) + b2p[2 * o + 1];
            if (RESID) { v0 += rp[2 * o]; v1 += rp[2 * o + 1]; }
            po[2 * o]     = fmaxf(v0, 0.f);
            po[2 * o + 1] = fmaxf(v1, 0.f);
        }
    }
}

extern "C" void kernel_launch(void* const* d_in, const int* in_sizes, int n_in,
                              void* d_out, int out_size, void* d_ws, size_t ws_size,
                              hipStream_t stream) {
    const float* x    = (const float*)d_in[0];
    const float* W1_0 = (const float*)d_in[2];
    const float* b1_0 = (const float*)d_in[3];
    const float* W2_0 = (const float*)d_in[4];
    const float* b2_0 = (const float*)d_in[5];
    const float* W1_1 = (const float*)d_in[6];
    const float* b1_1 = (const float*)d_in[7];
    const float* W2_1 = (const float*)d_in[8];
    const float* b2_1 = (const float*)d_in[9];
    const float* W1_2 = (const float*)d_in[10];
    const float* b1_2 = (const float*)d_in[11];
    const float* W2_2 = (const float*)d_in[12];
    const float* b2_2 = (const float*)d_in[13];
    float* outp = (float*)d_out;

    // workspace layout
    unsigned* plist = (unsigned*)d_ws;                            // NPTS*48 u32
    float* x0  = (float*)(plist + (size_t)NPTS * 48);             // 32768 x 64
    float* x1  = x0 + (size_t)NPTS * 64;                          // 32768 x 32
    float* sqb = x1 + (size_t)NPTS * 32;                          // 32768
    unsigned short* Whi0 = (unsigned short*)(sqb + NPTS);         // 6 x 4096 u16
    unsigned short* Wlo0 = Whi0 + 4096;
    unsigned short* Whi1 = Wlo0 + 4096;
    unsigned short* Wlo1 = Whi1 + 4096;
    unsigned short* Whi2 = Wlo1 + 4096;
    unsigned short* Wlo2 = Whi2 + 4096;
    unsigned short* Xhi = Wlo2 + 4096;                            // 32768 x 64 u16
    unsigned short* Xlo = Xhi + (size_t)NPTS * 64;                // 32768 x 64 u16
    int* nbr = (int*)(Xlo + (size_t)NPTS * 64);                   // 32768 x 6
    float* AB = (float*)(nbr + (size_t)NPTS * KNB);               // 32768 x 128

    const int fgrid  = NPTS / 64;       // prep_split: 4 thr/point, 512 blocks
    const int rgrid  = NPTS * 2 / 256;  // rescore: 2 thr/query, 256 blocks
    const int scgrid = 1024;            // 4096 waves of 32q x 512c
    const int pgrid  = NPTS / 64;       // 512 blocks x 768 thr

    prep_w<<<16, 256, 0, stream>>>(W1_0, W1_1, W1_2, Whi0, Wlo0, Whi1, Wlo1, Whi2, Wlo2);

    // ---- layer 0: x (32) -> x0 (64), relu ----
    prep_split<32><<<fgrid, 256, 0, stream>>>(x, Xhi, Xlo, sqb);
    ab_gemm<32, 64><<<NPTS / 32, 256, 0, stream>>>(Xhi, Xlo, Whi0, Wlo0, b1_0, AB);
    knn_scan<32><<<scgrid, 256, 0, stream>>>(Xhi, Xlo, sqb, plist);
    rescore<32><<<rgrid, 256, 0, stream>>>(x, sqb, plist, nbr);
    mlp_kernel<64, false, 5><<<pgrid, 768, 0, stream>>>(AB, nbr, W2_0, b2_0, nullptr, x0);

    // ---- layer 1: x0 (64) -> x1 (32), relu ----
    prep_split<64><<<fgrid, 256, 0, stream>>>(x0, Xhi, Xlo, sqb);
    ab_gemm<64, 32><<<NPTS / 64, 256, 0, stream>>>(Xhi, Xlo, Whi1, Wlo1, b1_1, AB);
    knn_scan<64><<<scgrid, 256, 0, stream>>>(Xhi, Xlo, sqb, plist);
    rescore<64><<<rgrid, 256, 0, stream>>>(x0, sqb, plist, nbr);
    mlp_kernel<32, false, 4><<<pgrid, 768, 0, stream>>>(AB, nbr, W2_1, b2_1, nullptr, x1);

    // ---- layer 2: x1 (32) -> out (64), +x0 residual, relu ----
    prep_split<32><<<fgrid, 256, 0, stream>>>(x1, Xhi, Xlo, sqb);
    ab_gemm<32, 64><<<NPTS / 32, 256, 0, stream>>>(Xhi, Xlo, Whi2, Wlo2, b1_2, AB);
    knn_scan<32><<<scgrid, 256, 0, stream>>>(Xhi, Xlo, sqb, plist);
    rescore<32><<<rgrid, 256, 0, stream>>>(x1, sqb, plist, nbr);
    mlp_kernel<64, true, 5><<<pgrid, 768, 0, stream>>>(AB, nbr, W2_2, b2_2, x0, outp);
}

// Round 19
// 394.505 us; speedup vs baseline: 1.1401x; 1.0269x over previous
//
#include <hip/hip_runtime.h>

#define NB   16
#define NN   2048
#define NPTS (NB * NN)
#define KNB  6

typedef __attribute__((ext_vector_type(8))) short short8;
typedef __attribute__((ext_vector_type(2))) float f32x2;
typedef __attribute__((ext_vector_type(4))) float f32x4;
typedef __attribute__((ext_vector_type(16))) float f32x16;
typedef const __attribute__((address_space(4))) float cfloat;
typedef const __attribute__((address_space(4))) f32x2 cf32x2;

__device__ __forceinline__ unsigned bf16_rne(float f) {
    unsigned u = __float_as_uint(f);
    return (u + 0x7fffu + ((u >> 16) & 1u)) >> 16;
}

// ---------------- weight prep: bf16 hi/lo of combined [2COUT][C] GEMM weights (verified R15) ----------------
__global__ void prep_w(const float* __restrict__ W10, const float* __restrict__ W11,
                       const float* __restrict__ W12,
                       unsigned short* __restrict__ Whi0, unsigned short* __restrict__ Wlo0,
                       unsigned short* __restrict__ Whi1, unsigned short* __restrict__ Wlo1,
                       unsigned short* __restrict__ Whi2, unsigned short* __restrict__ Wlo2) {
    int t = blockIdx.x * 256 + threadIdx.x;
    if (t >= 4096) return;
    {   // L0 / L2: n = t>>5 in [0,128), k = t&31
        const int n = t >> 5, k = t & 31;
        float v0, v2;
        if (n < 64) { v0 = W10[k * 64 + n] - W10[(32 + k) * 64 + n];
                      v2 = W12[k * 64 + n] - W12[(32 + k) * 64 + n]; }
        else        { v0 = W10[(32 + k) * 64 + (n - 64)];
                      v2 = W12[(32 + k) * 64 + (n - 64)]; }
        unsigned h0 = bf16_rne(v0);
        Whi0[t] = (unsigned short)h0;
        Wlo0[t] = (unsigned short)bf16_rne(v0 - __uint_as_float(h0 << 16));
        unsigned h2 = bf16_rne(v2);
        Whi2[t] = (unsigned short)h2;
        Wlo2[t] = (unsigned short)bf16_rne(v2 - __uint_as_float(h2 << 16));
    }
    {   // L1: n = t>>6 in [0,64), k = t&63
        const int n = t >> 6, k = t & 63;
        float v;
        if (n < 32) v = W11[k * 32 + n] - W11[(64 + k) * 32 + n];
        else        v = W11[(64 + k) * 32 + (n - 32)];
        unsigned h = bf16_rne(v);
        Whi1[t] = (unsigned short)h;
        Wlo1[t] = (unsigned short)bf16_rne(v - __uint_as_float(h << 16));
    }
}

// ---------------- FUSED prep + AB GEMM ----------------
// Phase 1 (conversion, verified R15 prep shape): the block converts exactly
// the point rows its GEMM tile needs (C=32: 32 pts, 8 thr/pt; C=64: 64 pts,
// 4 thr/pt), writes Xhi/Xlo + sq.  __syncthreads (drains the writes; same
// block -> same CU -> L1/L2-hot RAW).  Phase 2: verbatim R15 ab_gemm body.
// Removes 3 launches + dependency bubbles vs the split version.
template<int C, int COUT>
__global__ __launch_bounds__(256, 2)
void prep_gemm(const float* __restrict__ x,
               const unsigned short* __restrict__ Whi,
               const unsigned short* __restrict__ Wlo,
               const float* __restrict__ b1,
               unsigned short* __restrict__ Xhi,
               unsigned short* __restrict__ Xlo,
               float* __restrict__ sq, float* __restrict__ AB) {
    constexpr int KT  = C / 16;
    constexpr int N2  = 2 * COUT;
    constexpr int NCT = N2 / 32;            // col tiles: 4 (L0/2), 2 (L1)
    constexpr int RPB = 4 / NCT;            // row tiles per block: 1 / 2
    constexpr int PPB = RPB * 32;           // points per block: 32 / 64
    constexpr int TPP = 256 / PPB;          // threads per point: 8 / 4
    constexpr int Q   = C / TPP;            // elems per thread: 4 / 16
    const int tid = threadIdx.x;
    const int bid = blockIdx.x;

    // ---- phase 1: convert + sq ----
    {
        const int slot = tid & (TPP - 1);
        const int i    = bid * PPB + tid / TPP;
        float r[Q];
        const float4* rp = (const float4*)(x + (size_t)i * C + slot * Q);
#pragma unroll
        for (int c4 = 0; c4 < Q / 4; ++c4) {
            float4 f = rp[c4];
            r[4 * c4] = f.x; r[4 * c4 + 1] = f.y; r[4 * c4 + 2] = f.z; r[4 * c4 + 3] = f.w;
        }
        float s = 0.f;
#pragma unroll
        for (int c = 0; c < Q; ++c) s = fmaf(r[c], r[c], s);
#pragma unroll
        for (int d = 1; d < TPP; d <<= 1) s += __shfl_xor(s, d);
        if (slot == 0) sq[i] = s;

#pragma unroll
        for (int cc = 0; cc < Q; cc += 4) {
            unsigned uh0, uh1, ul0, ul1;
            {
                const unsigned h0 = bf16_rne(r[cc]);
                const unsigned h1 = bf16_rne(r[cc + 1]);
                const unsigned h2 = bf16_rne(r[cc + 2]);
                const unsigned h3 = bf16_rne(r[cc + 3]);
                const unsigned l0 = bf16_rne(r[cc]     - __uint_as_float(h0 << 16));
                const unsigned l1 = bf16_rne(r[cc + 1] - __uint_as_float(h1 << 16));
                const unsigned l2 = bf16_rne(r[cc + 2] - __uint_as_float(h2 << 16));
                const unsigned l3 = bf16_rne(r[cc + 3] - __uint_as_float(h3 << 16));
                uh0 = h0 | (h1 << 16); uh1 = h2 | (h3 << 16);
                ul0 = l0 | (l1 << 16); ul1 = l2 | (l3 << 16);
            }
            const size_t off = (size_t)i * C + slot * Q + cc;
            *(uint2*)(Xhi + off) = make_uint2(uh0, uh1);
            *(uint2*)(Xlo + off) = make_uint2(ul0, ul1);
        }
    }
    __syncthreads();   // phase-1 writes drained & visible block-wide (L1-hot)

    // ---- phase 2: AB GEMM (verbatim R15 ab_gemm body) ----
    const int w    = __builtin_amdgcn_readfirstlane(tid >> 6);
    const int lane = tid & 63;
    const int n31  = lane & 31;
    const int lh   = lane >> 5;
    const int rt   = bid * RPB + w / NCT;
    const int ct   = w % NCT;
    const int p0   = rt * 32;

    short8 ah[KT], al[KT], wh[KT], wl[KT];
#pragma unroll
    for (int kt = 0; kt < KT; ++kt) {
        const size_t poff = (size_t)(p0 + n31) * C + kt * 16 + lh * 8;
        ah[kt] = *(const short8*)(Xhi + poff);
        al[kt] = *(const short8*)(Xlo + poff);
        const size_t woff = (size_t)(ct * 32 + n31) * C + kt * 16 + lh * 8;
        wh[kt] = *(const short8*)(Whi + woff);
        wl[kt] = *(const short8*)(Wlo + woff);
    }

    f32x16 acc = {0.f};
#pragma unroll
    for (int kt = 0; kt < KT; ++kt) {
        acc = __builtin_amdgcn_mfma_f32_32x32x16_bf16(ah[kt], wh[kt], acc, 0, 0, 0);
        acc = __builtin_amdgcn_mfma_f32_32x32x16_bf16(ah[kt], wl[kt], acc, 0, 0, 0);
        acc = __builtin_amdgcn_mfma_f32_32x32x16_bf16(al[kt], wh[kt], acc, 0, 0, 0);
    }

    const int nc = ct * 32 + n31;           // output col in [0, 2COUT)
    const float bias = (ct < COUT / 32) ? b1[nc] : 0.f;   // A-tile test is wave-uniform
#pragma unroll
    for (int r = 0; r < 16; ++r) {
        const int pt = p0 + (r & 3) + 8 * (r >> 2) + 4 * lh;
        AB[(size_t)pt * N2 + nc] = acc[r] + bias;
    }
}

// sorted ascending top-6 insert via pure min/max network (2 VALU / level).
__device__ __forceinline__ void insert6f(float s, float* dl) {
#pragma unroll
    for (int k = 0; k < 6; ++k) {
        const float a = dl[k];
        dl[k] = fminf(s, a);
        s = fmaxf(s, a);
    }
}

// ---------------- MFMA kNN scan (32x32 tiles, TRIPLE-buffered LDS staging; verified R18) ----------------
template<int C>
__global__ __launch_bounds__(256, 4)
void knn_scan(const unsigned short* __restrict__ Xhi,
              const unsigned short* __restrict__ Xlo,
              const float* __restrict__ sqv,
              unsigned* __restrict__ plist) {
    constexpr int KT    = C / 16;           // K=16 tiles per product
    constexpr int SR    = C / 4;            // 16B slots per LDS row (hi+lo)
    constexpr int ROWB  = SR * 16;          // 128 / 256 bytes per row
    constexpr int STEPB = 32 * ROWB;        // 4 KB / 8 KB per step buffer
    constexpr int LPT   = STEPB / 16 / 256; // 1 / 2 loads per thread per step
    __shared__ __align__(16) char sm[3 * STEPB];

    const int tid  = threadIdx.x;
    const int w    = __builtin_amdgcn_readfirstlane(tid >> 6);
    const int bid  = blockIdx.x;
    const int swz  = ((bid & 7) << 7) | (bid >> 3);   // 1024 blocks, 128/XCD
    const int b    = swz >> 6;              // batch (2 per XCD)
    const int sp   = (swz >> 4) & 3;        // candidate quarter
    const int qg   = swz & 15;              // query group of 4 tiles
    const int qt   = qg * 4 + w;            // this wave's query tile (32 q)
    const int lane = tid & 63;
    const int q31  = lane & 31;
    const int lh   = lane >> 5;
    const int base = b * NN;
    const int qloc = qt * 32 + q31;         // batch-local query index

    // persistent query fragments
    short8 bh[KT], bl[KT];
#pragma unroll
    for (int kt = 0; kt < KT; ++kt) {
        const size_t off = (size_t)(base + qloc) * C + kt * 16 + lh * 8;
        bh[kt] = *(const short8*)(Xhi + off);
        bl[kt] = *(const short8*)(Xlo + off);
    }

    float dl[6];
#pragma unroll
    for (int k = 0; k < 6; ++k) dl[k] = 1e30f;

    const int jbeg   = sp * (NN / 4);
    const int selfjb = qt * 32;             // only step that can contain self

    // staging source pointers: thread's LDS slot sidx -> (row, slot);
    // content = SRC[row][slot ^ (row&(SR-1))] (XOR involution; reader undoes it)
    const unsigned short* src[LPT];
#pragma unroll
    for (int l = 0; l < LPT; ++l) {
        const int sidx = tid + l * 256;
        const int row  = sidx / SR;
        const int slot = sidx % SR;
        const int u    = slot ^ (row & (SR - 1));
        const unsigned short* bp = (u < SR / 2) ? Xhi : Xlo;
        src[l] = bp + (size_t)(base + jbeg + row) * C + (u & (SR / 2 - 1)) * 8;
    }

    // per-lane ds-read constants
    const int m       = q31 & (SR - 1);
    const int rowbase = q31 * ROWB;
    const float* sqp  = sqv + base + jbeg + lh * 4;
    float4 s4[4];

#define STAGE(BUF) do {                                                        \
    _Pragma("unroll")                                                          \
    for (int l = 0; l < LPT; ++l) {                                            \
        __builtin_amdgcn_global_load_lds(                                      \
            (const __attribute__((address_space(1))) void*)src[l],             \
            (__attribute__((address_space(3))) void*)                          \
                (sm + (BUF) * STEPB + l * 4096 + w * 1024),                    \
            16, 0, 0);                                                         \
        src[l] += 32 * C;                                                      \
    }                                                                          \
} while (0)

#define COMPUTE(BUF, JB) do {                                                  \
    const char* smc = sm + (BUF) * STEPB;                                      \
    f32x16 acc = {0.f};                                                        \
    _Pragma("unroll")                                                          \
    for (int kt = 0; kt < KT; ++kt) {                                          \
        const int uh = kt * 2 + lh;                                            \
        const int ul = 2 * KT + kt * 2 + lh;                                   \
        const short8 ah = *(const short8*)(smc + rowbase + ((uh ^ m) << 4));   \
        const short8 al = *(const short8*)(smc + rowbase + ((ul ^ m) << 4));   \
        acc = __builtin_amdgcn_mfma_f32_32x32x16_bf16(ah, bh[kt], acc, 0, 0, 0); \
        acc = __builtin_amdgcn_mfma_f32_32x32x16_bf16(ah, bl[kt], acc, 0, 0, 0); \
        acc = __builtin_amdgcn_mfma_f32_32x32x16_bf16(al, bh[kt], acc, 0, 0, 0); \
    }                                                                          \
    const unsigned ebase = (unsigned)(((JB) - jbeg) >> 1);   /* step*16 */     \
    const bool selfstep = ((JB) == selfjb);                                    \
    _Pragma("unroll")                                                          \
    for (int g4 = 0; g4 < 4; ++g4) {                                           \
        _Pragma("unroll")                                                      \
        for (int rr = 0; rr < 4; ++rr) {                                       \
            const int r = g4 * 4 + rr;                                         \
            float sc = fmaf(-2.f, acc[r],                                      \
                rr == 0 ? s4[g4].x : rr == 1 ? s4[g4].y :                      \
                rr == 2 ? s4[g4].z : s4[g4].w);                                \
            sc = __uint_as_float((__float_as_uint(sc) & 0xFFFFFF00u) |         \
                                 (ebase + (unsigned)((r & 3) + 4 * (r >> 2)))); \
            if (selfstep) {                                                    \
                const int rowr = (r & 3) + 8 * (r >> 2) + 4 * lh;              \
                sc = (rowr == q31) ? 1e30f : sc;                               \
            }                                                                  \
            insert6f(sc, dl);                                                  \
        }                                                                      \
    }                                                                          \
} while (0)

    STAGE(0);                               // prologue: step 0 in flight
    int jb = jbeg, cur = 0, nxt = 1;
#pragma unroll 1
    for (int st = 0; st < 15; ++st) {
#pragma unroll
        for (int g4 = 0; g4 < 4; ++g4) s4[g4] = *(const float4*)(sqp + g4 * 8);
        asm volatile("" ::: "memory");      // pin: sq loads issue BEFORE stage
        STAGE(nxt);                         // step st+1 in flight
        if constexpr (C == 32) asm volatile("s_waitcnt vmcnt(5)" ::: "memory");
        else                   asm volatile("s_waitcnt vmcnt(6)" ::: "memory");
        __builtin_amdgcn_s_barrier();       // step-st data landed (all waves)
        COMPUTE(cur, jb);
        jb += 32; sqp += 32;
        cur = nxt;
        nxt = (nxt == 2) ? 0 : nxt + 1;
    }
    {   // epilogue: last step, drain
#pragma unroll
        for (int g4 = 0; g4 < 4; ++g4) s4[g4] = *(const float4*)(sqp + g4 * 8);
        asm volatile("s_waitcnt vmcnt(0)" ::: "memory");
        __builtin_amdgcn_s_barrier();
        COMPUTE(cur, jb);
    }
#undef STAGE
#undef COMPUTE

    // write this lane's sorted sublist as sortable-transformed u32 keys
    unsigned* o = plist + (size_t)(base + qloc) * 48 + (sp * 2 + lh) * 6;
#pragma unroll
    for (int k = 0; k < 6; ++k) {
        const unsigned bits = __float_as_uint(dl[k]);
        o[k] = bits ^ ((bits & 0x80000000u) ? 0xFFFFFFFFu : 0x80000000u);
    }
}

// ---------------- exact rescore: 2 threads/query (verified R11/R15) ----------------
template<int C>
__global__ __launch_bounds__(256)
void rescore(const float* __restrict__ x, const float* __restrict__ sqv,
             const unsigned* __restrict__ plist, int* __restrict__ nbr) {
    const int bid  = blockIdx.x;
    const int bsw  = ((bid & 7) << 5) | (bid >> 3);   // 256 blocks, bijective
    const int gi   = bsw * 256 + threadIdx.x;
    const int i    = gi >> 1;
    const int slot = gi & 1;

    const unsigned* pr = plist + (size_t)i * 48 + slot * 24;

    unsigned long long best[7];
#pragma unroll
    for (int k = 0; k < 7; ++k) best[k] = ~0ull;
    for (int z4 = 0; z4 < 4; ++z4) {
        const unsigned* p = pr + z4 * 6;
        const unsigned zg = (unsigned)(slot * 4 + z4);
        for (int e = 0; e < 6; ++e) {
            unsigned long long v = ((unsigned long long)p[e] << 3) | zg;
            if (v >= best[6]) break;      // sublist ascending
            best[6] = v;
#pragma unroll
            for (int k = 5; k >= 0; --k) {
                if (best[k + 1] < best[k]) {
                    unsigned long long t = best[k]; best[k] = best[k + 1]; best[k + 1] = t;
                }
            }
        }
    }

    const int base = i & ~(NN - 1);
    float4 qv[C / 4];
    const float4* qp = (const float4*)(x + (size_t)i * C);
#pragma unroll
    for (int t = 0; t < C / 4; ++t) qv[t] = qp[t];

    unsigned long long out6[6];
#pragma unroll
    for (int k = 0; k < 6; ++k) out6[k] = ~0ull;

    for (int m = 0; m < 7; ++m) {
        const unsigned u32k = (unsigned)(best[m] >> 3);
        const int z = (int)(best[m] & 7ull);
        const unsigned orig = (u32k & 0x80000000u) ? (u32k ^ 0x80000000u) : ~u32k;
        const int e = (int)(orig & 255u);
        const int idx = e & 15;
        const int jloc = (z >> 1) * (NN / 4) + (e >> 4) * 32 +
                         (idx & 3) + 8 * (idx >> 2) + (z & 1) * 4;

        const float4* cp = (const float4*)(x + (size_t)(base + jloc) * C);
        float d0 = 0.f, d1 = 0.f, d2 = 0.f, d3 = 0.f;
#pragma unroll
        for (int t = 0; t < C / 4; ++t) {
            float4 a = cp[t];
            d0 = fmaf(a.x, qv[t].x, d0);
            d1 = fmaf(a.y, qv[t].y, d1);
            d2 = fmaf(a.z, qv[t].z, d2);
            d3 = fmaf(a.w, qv[t].w, d3);
        }
        const float s = fmaf(-2.f, (d0 + d1) + (d2 + d3), sqv[base + jloc]);
        unsigned u = __float_as_uint(s);
        u ^= (u & 0x80000000u) ? 0xFFFFFFFFu : 0x80000000u;
        unsigned long long key = ((unsigned long long)u << 11) | (unsigned)jloc;
#pragma unroll
        for (int k = 0; k < 6; ++k) {
            const unsigned long long ok = out6[k];
            const bool c = key < ok;
            out6[k] = c ? key : ok;
            key     = c ? ok  : key;
        }
    }

    // exchange per-half exact top-6 with partner; merge to final top-6
    unsigned long long fin[6];
#pragma unroll
    for (int k = 0; k < 6; ++k) fin[k] = out6[k];
#pragma unroll
    for (int k = 0; k < 6; ++k) {
        const unsigned long long v = out6[k];
        const unsigned lo = __shfl_xor((unsigned)v, 1);
        const unsigned hi = __shfl_xor((unsigned)(v >> 32), 1);
        unsigned long long key = ((unsigned long long)hi << 32) | lo;
#pragma unroll
        for (int q = 0; q < 6; ++q) {
            const unsigned long long ok = fin[q];
            const bool c = key < ok;
            fin[q] = c ? key : ok;
            key    = c ? ok  : key;
        }
    }
#pragma unroll
    for (int k = 0; k < 3; ++k)
        nbr[i * KNB + slot * 3 + k] = base + (int)(fin[slot * 3 + k] & 2047ull);
}

// ---------------- edge MLP kernel (gathered A/B from the MFMA-computed AB; verified R15) ----------------
template<int COUT, bool RESID, int MINW>
__global__ __launch_bounds__(768, MINW)
void mlp_kernel(const float* __restrict__ AB, const int* __restrict__ nbr,
                const float* __restrict__ W2, const float* __restrict__ b2,
                const float* __restrict__ resid, float* __restrict__ out) {
    constexpr int HALF = COUT / 2;
    constexpr int NQ   = COUT / 4;
    constexpr int N2   = 2 * COUT;
    constexpr int RS = HALF + 4;
    __shared__ float Buf[2][3][64][RS];

    const int tid  = threadIdx.x;
    const int lane = tid & 63;
    const int wv   = __builtin_amdgcn_readfirstlane(tid >> 6);  // 0..11
    const int oh   = wv / 6;                                    // output half
    const int w6   = wv % 6;                                    // neighbor
    const int bid  = blockIdx.x;
    const int bsw  = ((bid & 7) << 6) | (bid >> 3);             // XCD swizzle, 512 blocks
    const int i    = bsw * 64 + lane;
    const int j    = nbr[i * KNB + w6];

    f32x2 uacc[HALF / 2];
#pragma unroll
    for (int o = 0; o < HALF / 2; ++o) uacc[o] = (f32x2){0.f, 0.f};

    cfloat* W2c = (cfloat*)(uintptr_t)W2;
    const float* Ap = AB + (size_t)i * N2;
    const float* Bp = AB + (size_t)j * N2 + COUT;

    const int qofs = (wv * 3) & (NQ - 1);    // wave-staggered op start

#pragma unroll 2
    for (int qi = 0; qi < NQ; ++qi) {
        const int oq = (qi + qofs) & (NQ - 1);
        const float4 a4 = *(const float4*)(Ap + 4 * oq);
        const float4 b4 = *(const float4*)(Bp + 4 * oq);
#pragma unroll
        for (int rr = 0; rr < 4; ++rr) {
            const int op = oq * 4 + rr;
            const float aop = rr == 0 ? a4.x : rr == 1 ? a4.y : rr == 2 ? a4.z : a4.w;
            const float bop = rr == 0 ? b4.x : rr == 1 ? b4.y : rr == 2 ? b4.z : b4.w;
            const float h = fmaxf(aop + bop, 0.f);
            cf32x2* w2p = (cf32x2*)(W2c + (size_t)op * COUT + oh * HALF);
            const f32x2 hv = {h, h};
#pragma unroll
            for (int o = 0; o < HALF / 2; ++o)
                uacc[o] += w2p[o] * hv;          // v_pk_fma_f32
        }
    }

    // per-half 6 -> 1 max tree over neighbor waves
    if (w6 >= 3) {
#pragma unroll
        for (int o = 0; o < HALF / 2; ++o) {
            Buf[oh][w6 - 3][lane][2 * o]     = uacc[o].x;
            Buf[oh][w6 - 3][lane][2 * o + 1] = uacc[o].y;
        }
    }
    __syncthreads();
    if (w6 < 3) {
#pragma unroll
        for (int o = 0; o < HALF / 2; ++o) {
            uacc[o].x = fmaxf(uacc[o].x, Buf[oh][w6][lane][2 * o]);
            uacc[o].y = fmaxf(uacc[o].y, Buf[oh][w6][lane][2 * o + 1]);
        }
    }
    __syncthreads();
    if (w6 == 1 || w6 == 2) {
#pragma unroll
        for (int o = 0; o < HALF / 2; ++o) {
            Buf[oh][w6][lane][2 * o]     = uacc[o].x;
            Buf[oh][w6][lane][2 * o + 1] = uacc[o].y;
        }
    }
    __syncthreads();
    if (w6 == 0) {
        float* po = out + (size_t)i * COUT + oh * HALF;
        const float* b2p = b2 + oh * HALF;
        const float* rp  = RESID ? (resid + (size_t)i * COUT + oh * HALF) : nullptr;
#pragma unroll
        for (int o = 0; o < HALF / 2; ++o) {
            float v0 = fmaxf(uacc[o].x,
                             fmaxf(Buf[oh][1][lane][2 * o], Buf[oh][2][lane][2 * o])) + b2p[2 * o];
            float v1 = fmaxf(uacc[o].y,
                             fmaxf(Buf[oh][1][lane][2 * o + 1], Buf[oh][2][lane][2 * o + 1])) + b2p[2 * o + 1];
            if (RESID) { v0 += rp[2 * o]; v1 += rp[2 * o + 1]; }
            po[2 * o]     = fmaxf(v0, 0.f);
            po[2 * o + 1] = fmaxf(v1, 0.f);
        }
    }
}

extern "C" void kernel_launch(void* const* d_in, const int* in_sizes, int n_in,
                              void* d_out, int out_size, void* d_ws, size_t ws_size,
                              hipStream_t stream) {
    const float* x    = (const float*)d_in[0];
    const float* W1_0 = (const float*)d_in[2];
    const float* b1_0 = (const float*)d_in[3];
    const float* W2_0 = (const float*)d_in[4];
    const float* b2_0 = (const float*)d_in[5];
    const float* W1_1 = (const float*)d_in[6];
    const float* b1_1 = (const float*)d_in[7];
    const float* W2_1 = (const float*)d_in[8];
    const float* b2_1 = (const float*)d_in[9];
    const float* W1_2 = (const float*)d_in[10];
    const float* b1_2 = (const float*)d_in[11];
    const float* W2_2 = (const float*)d_in[12];
    const float* b2_2 = (const float*)d_in[13];
    float* outp = (float*)d_out;

    // workspace layout
    unsigned* plist = (unsigned*)d_ws;                            // NPTS*48 u32
    float* x0  = (float*)(plist + (size_t)NPTS * 48);             // 32768 x 64
    float* x1  = x0 + (size_t)NPTS * 64;                          // 32768 x 32
    float* sqb = x1 + (size_t)NPTS * 32;                          // 32768
    unsigned short* Whi0 = (unsigned short*)(sqb + NPTS);         // 6 x 4096 u16
    unsigned short* Wlo0 = Whi0 + 4096;
    unsigned short* Whi1 = Wlo0 + 4096;
    unsigned short* Wlo1 = Whi1 + 4096;
    unsigned short* Whi2 = Wlo1 + 4096;
    unsigned short* Wlo2 = Whi2 + 4096;
    unsigned short* Xhi = Wlo2 + 4096;                            // 32768 x 64 u16
    unsigned short* Xlo = Xhi + (size_t)NPTS * 64;                // 32768 x 64 u16
    int* nbr = (int*)(Xlo + (size_t)NPTS * 64);                   // 32768 x 6
    float* AB = (float*)(nbr + (size_t)NPTS * KNB);               // 32768 x 128

    const int rgrid  = NPTS * 2 / 256;  // rescore: 2 thr/query, 256 blocks
    const int scgrid = 1024;            // 4096 waves of 32q x 512c
    const int pgrid  = NPTS / 64;       // 512 blocks x 768 thr

    prep_w<<<16, 256, 0, stream>>>(W1_0, W1_1, W1_2, Whi0, Wlo0, Whi1, Wlo1, Whi2, Wlo2);

    // ---- layer 0: x (32) -> x0 (64), relu ----
    prep_gemm<32, 64><<<NPTS / 32, 256, 0, stream>>>(x, Whi0, Wlo0, b1_0, Xhi, Xlo, sqb, AB);
    knn_scan<32><<<scgrid, 256, 0, stream>>>(Xhi, Xlo, sqb, plist);
    rescore<32><<<rgrid, 256, 0, stream>>>(x, sqb, plist, nbr);
    mlp_kernel<64, false, 5><<<pgrid, 768, 0, stream>>>(AB, nbr, W2_0, b2_0, nullptr, x0);

    // ---- layer 1: x0 (64) -> x1 (32), relu ----
    prep_gemm<64, 32><<<NPTS / 64, 256, 0, stream>>>(x0, Whi1, Wlo1, b1_1, Xhi, Xlo, sqb, AB);
    knn_scan<64><<<scgrid, 256, 0, stream>>>(Xhi, Xlo, sqb, plist);
    rescore<64><<<rgrid, 256, 0, stream>>>(x0, sqb, plist, nbr);
    mlp_kernel<32, false, 4><<<pgrid, 768, 0, stream>>>(AB, nbr, W2_1, b2_1, nullptr, x1);

    // ---- layer 2: x1 (32) -> out (64), +x0 residual, relu ----
    prep_gemm<32, 64><<<NPTS / 32, 256, 0, stream>>>(x1, Whi2, Wlo2, b1_2, Xhi, Xlo, sqb, AB);
    knn_scan<32><<<scgrid, 256, 0, stream>>>(Xhi, Xlo, sqb, plist);
    rescore<32><<<rgrid, 256, 0, stream>>>(x1, sqb, plist, nbr);
    mlp_kernel<64, true, 5><<<pgrid, 768, 0, stream>>>(AB, nbr, W2_2, b2_2, x0, outp);
}

// Round 20
// 386.376 us; speedup vs baseline: 1.1641x; 1.0210x over previous
//
#include <hip/hip_runtime.h>

#define NB   16
#define NN   2048
#define NPTS (NB * NN)
#define KNB  6

typedef __attribute__((ext_vector_type(8))) short short8;
typedef __attribute__((ext_vector_type(2))) float f32x2;
typedef __attribute__((ext_vector_type(4))) float f32x4;
typedef __attribute__((ext_vector_type(16))) float f32x16;
typedef const __attribute__((address_space(4))) float cfloat;
typedef const __attribute__((address_space(4))) f32x2 cf32x2;

__device__ __forceinline__ unsigned bf16_rne(float f) {
    unsigned u = __float_as_uint(f);
    return (u + 0x7fffu + ((u >> 16) & 1u)) >> 16;
}

// ---------------- weight prep: bf16 hi/lo of combined [2COUT][C] GEMM weights (verified R15) ----------------
__global__ void prep_w(const float* __restrict__ W10, const float* __restrict__ W11,
                       const float* __restrict__ W12,
                       unsigned short* __restrict__ Whi0, unsigned short* __restrict__ Wlo0,
                       unsigned short* __restrict__ Whi1, unsigned short* __restrict__ Wlo1,
                       unsigned short* __restrict__ Whi2, unsigned short* __restrict__ Wlo2) {
    int t = blockIdx.x * 256 + threadIdx.x;
    if (t >= 4096) return;
    {   // L0 / L2: n = t>>5 in [0,128), k = t&31
        const int n = t >> 5, k = t & 31;
        float v0, v2;
        if (n < 64) { v0 = W10[k * 64 + n] - W10[(32 + k) * 64 + n];
                      v2 = W12[k * 64 + n] - W12[(32 + k) * 64 + n]; }
        else        { v0 = W10[(32 + k) * 64 + (n - 64)];
                      v2 = W12[(32 + k) * 64 + (n - 64)]; }
        unsigned h0 = bf16_rne(v0);
        Whi0[t] = (unsigned short)h0;
        Wlo0[t] = (unsigned short)bf16_rne(v0 - __uint_as_float(h0 << 16));
        unsigned h2 = bf16_rne(v2);
        Whi2[t] = (unsigned short)h2;
        Wlo2[t] = (unsigned short)bf16_rne(v2 - __uint_as_float(h2 << 16));
    }
    {   // L1: n = t>>6 in [0,64), k = t&63
        const int n = t >> 6, k = t & 63;
        float v;
        if (n < 32) v = W11[k * 32 + n] - W11[(64 + k) * 32 + n];
        else        v = W11[(64 + k) * 32 + (n - 32)];
        unsigned h = bf16_rne(v);
        Whi1[t] = (unsigned short)h;
        Wlo1[t] = (unsigned short)bf16_rne(v - __uint_as_float(h << 16));
    }
}

// ---------------- FUSED prep + AB GEMM (verified R19) ----------------
template<int C, int COUT>
__global__ __launch_bounds__(256, 2)
void prep_gemm(const float* __restrict__ x,
               const unsigned short* __restrict__ Whi,
               const unsigned short* __restrict__ Wlo,
               const float* __restrict__ b1,
               unsigned short* __restrict__ Xhi,
               unsigned short* __restrict__ Xlo,
               float* __restrict__ sq, float* __restrict__ AB) {
    constexpr int KT  = C / 16;
    constexpr int N2  = 2 * COUT;
    constexpr int NCT = N2 / 32;            // col tiles: 4 (L0/2), 2 (L1)
    constexpr int RPB = 4 / NCT;            // row tiles per block: 1 / 2
    constexpr int PPB = RPB * 32;           // points per block: 32 / 64
    constexpr int TPP = 256 / PPB;          // threads per point: 8 / 4
    constexpr int Q   = C / TPP;            // elems per thread: 4 / 16
    const int tid = threadIdx.x;
    const int bid = blockIdx.x;

    // ---- phase 1: convert + sq ----
    {
        const int slot = tid & (TPP - 1);
        const int i    = bid * PPB + tid / TPP;
        float r[Q];
        const float4* rp = (const float4*)(x + (size_t)i * C + slot * Q);
#pragma unroll
        for (int c4 = 0; c4 < Q / 4; ++c4) {
            float4 f = rp[c4];
            r[4 * c4] = f.x; r[4 * c4 + 1] = f.y; r[4 * c4 + 2] = f.z; r[4 * c4 + 3] = f.w;
        }
        float s = 0.f;
#pragma unroll
        for (int c = 0; c < Q; ++c) s = fmaf(r[c], r[c], s);
#pragma unroll
        for (int d = 1; d < TPP; d <<= 1) s += __shfl_xor(s, d);
        if (slot == 0) sq[i] = s;

#pragma unroll
        for (int cc = 0; cc < Q; cc += 4) {
            unsigned uh0, uh1, ul0, ul1;
            {
                const unsigned h0 = bf16_rne(r[cc]);
                const unsigned h1 = bf16_rne(r[cc + 1]);
                const unsigned h2 = bf16_rne(r[cc + 2]);
                const unsigned h3 = bf16_rne(r[cc + 3]);
                const unsigned l0 = bf16_rne(r[cc]     - __uint_as_float(h0 << 16));
                const unsigned l1 = bf16_rne(r[cc + 1] - __uint_as_float(h1 << 16));
                const unsigned l2 = bf16_rne(r[cc + 2] - __uint_as_float(h2 << 16));
                const unsigned l3 = bf16_rne(r[cc + 3] - __uint_as_float(h3 << 16));
                uh0 = h0 | (h1 << 16); uh1 = h2 | (h3 << 16);
                ul0 = l0 | (l1 << 16); ul1 = l2 | (l3 << 16);
            }
            const size_t off = (size_t)i * C + slot * Q + cc;
            *(uint2*)(Xhi + off) = make_uint2(uh0, uh1);
            *(uint2*)(Xlo + off) = make_uint2(ul0, ul1);
        }
    }
    __syncthreads();   // phase-1 writes drained & visible block-wide (L1-hot)

    // ---- phase 2: AB GEMM (verbatim R15 ab_gemm body) ----
    const int w    = __builtin_amdgcn_readfirstlane(tid >> 6);
    const int lane = tid & 63;
    const int n31  = lane & 31;
    const int lh   = lane >> 5;
    const int rt   = bid * RPB + w / NCT;
    const int ct   = w % NCT;
    const int p0   = rt * 32;

    short8 ah[KT], al[KT], wh[KT], wl[KT];
#pragma unroll
    for (int kt = 0; kt < KT; ++kt) {
        const size_t poff = (size_t)(p0 + n31) * C + kt * 16 + lh * 8;
        ah[kt] = *(const short8*)(Xhi + poff);
        al[kt] = *(const short8*)(Xlo + poff);
        const size_t woff = (size_t)(ct * 32 + n31) * C + kt * 16 + lh * 8;
        wh[kt] = *(const short8*)(Whi + woff);
        wl[kt] = *(const short8*)(Wlo + woff);
    }

    f32x16 acc = {0.f};
#pragma unroll
    for (int kt = 0; kt < KT; ++kt) {
        acc = __builtin_amdgcn_mfma_f32_32x32x16_bf16(ah[kt], wh[kt], acc, 0, 0, 0);
        acc = __builtin_amdgcn_mfma_f32_32x32x16_bf16(ah[kt], wl[kt], acc, 0, 0, 0);
        acc = __builtin_amdgcn_mfma_f32_32x32x16_bf16(al[kt], wh[kt], acc, 0, 0, 0);
    }

    const int nc = ct * 32 + n31;           // output col in [0, 2COUT)
    const float bias = (ct < COUT / 32) ? b1[nc] : 0.f;   // A-tile test is wave-uniform
#pragma unroll
    for (int r = 0; r < 16; ++r) {
        const int pt = p0 + (r & 3) + 8 * (r >> 2) + 4 * lh;
        AB[(size_t)pt * N2 + nc] = acc[r] + bias;
    }
}

// sorted ascending top-6 insert via pure min/max network (2 VALU / level).
__device__ __forceinline__ void insert6f(float s, float* dl) {
#pragma unroll
    for (int k = 0; k < 6; ++k) {
        const float a = dl[k];
        dl[k] = fminf(s, a);
        s = fmaxf(s, a);
    }
}

// ---------------- MFMA kNN scan (32x32 tiles, TRIPLE-buffered LDS staging; verified R18) ----------------
template<int C>
__global__ __launch_bounds__(256, 4)
void knn_scan(const unsigned short* __restrict__ Xhi,
              const unsigned short* __restrict__ Xlo,
              const float* __restrict__ sqv,
              unsigned* __restrict__ plist) {
    constexpr int KT    = C / 16;           // K=16 tiles per product
    constexpr int SR    = C / 4;            // 16B slots per LDS row (hi+lo)
    constexpr int ROWB  = SR * 16;          // 128 / 256 bytes per row
    constexpr int STEPB = 32 * ROWB;        // 4 KB / 8 KB per step buffer
    constexpr int LPT   = STEPB / 16 / 256; // 1 / 2 loads per thread per step
    __shared__ __align__(16) char sm[3 * STEPB];

    const int tid  = threadIdx.x;
    const int w    = __builtin_amdgcn_readfirstlane(tid >> 6);
    const int bid  = blockIdx.x;
    const int swz  = ((bid & 7) << 7) | (bid >> 3);   // 1024 blocks, 128/XCD
    const int b    = swz >> 6;              // batch (2 per XCD)
    const int sp   = (swz >> 4) & 3;        // candidate quarter
    const int qg   = swz & 15;              // query group of 4 tiles
    const int qt   = qg * 4 + w;            // this wave's query tile (32 q)
    const int lane = tid & 63;
    const int q31  = lane & 31;
    const int lh   = lane >> 5;
    const int base = b * NN;
    const int qloc = qt * 32 + q31;         // batch-local query index

    // persistent query fragments
    short8 bh[KT], bl[KT];
#pragma unroll
    for (int kt = 0; kt < KT; ++kt) {
        const size_t off = (size_t)(base + qloc) * C + kt * 16 + lh * 8;
        bh[kt] = *(const short8*)(Xhi + off);
        bl[kt] = *(const short8*)(Xlo + off);
    }

    float dl[6];
#pragma unroll
    for (int k = 0; k < 6; ++k) dl[k] = 1e30f;

    const int jbeg   = sp * (NN / 4);
    const int selfjb = qt * 32;             // only step that can contain self

    // staging source pointers: thread's LDS slot sidx -> (row, slot);
    // content = SRC[row][slot ^ (row&(SR-1))] (XOR involution; reader undoes it)
    const unsigned short* src[LPT];
#pragma unroll
    for (int l = 0; l < LPT; ++l) {
        const int sidx = tid + l * 256;
        const int row  = sidx / SR;
        const int slot = sidx % SR;
        const int u    = slot ^ (row & (SR - 1));
        const unsigned short* bp = (u < SR / 2) ? Xhi : Xlo;
        src[l] = bp + (size_t)(base + jbeg + row) * C + (u & (SR / 2 - 1)) * 8;
    }

    // per-lane ds-read constants
    const int m       = q31 & (SR - 1);
    const int rowbase = q31 * ROWB;
    const float* sqp  = sqv + base + jbeg + lh * 4;
    float4 s4[4];

#define STAGE(BUF) do {                                                        \
    _Pragma("unroll")                                                          \
    for (int l = 0; l < LPT; ++l) {                                            \
        __builtin_amdgcn_global_load_lds(                                      \
            (const __attribute__((address_space(1))) void*)src[l],             \
            (__attribute__((address_space(3))) void*)                          \
                (sm + (BUF) * STEPB + l * 4096 + w * 1024),                    \
            16, 0, 0);                                                         \
        src[l] += 32 * C;                                                      \
    }                                                                          \
} while (0)

#define COMPUTE(BUF, JB) do {                                                  \
    const char* smc = sm + (BUF) * STEPB;                                      \
    f32x16 acc = {0.f};                                                        \
    _Pragma("unroll")                                                          \
    for (int kt = 0; kt < KT; ++kt) {                                          \
        const int uh = kt * 2 + lh;                                            \
        const int ul = 2 * KT + kt * 2 + lh;                                   \
        const short8 ah = *(const short8*)(smc + rowbase + ((uh ^ m) << 4));   \
        const short8 al = *(const short8*)(smc + rowbase + ((ul ^ m) << 4));   \
        acc = __builtin_amdgcn_mfma_f32_32x32x16_bf16(ah, bh[kt], acc, 0, 0, 0); \
        acc = __builtin_amdgcn_mfma_f32_32x32x16_bf16(ah, bl[kt], acc, 0, 0, 0); \
        acc = __builtin_amdgcn_mfma_f32_32x32x16_bf16(al, bh[kt], acc, 0, 0, 0); \
    }                                                                          \
    const unsigned ebase = (unsigned)(((JB) - jbeg) >> 1);   /* step*16 */     \
    const bool selfstep = ((JB) == selfjb);                                    \
    _Pragma("unroll")                                                          \
    for (int g4 = 0; g4 < 4; ++g4) {                                           \
        _Pragma("unroll")                                                      \
        for (int rr = 0; rr < 4; ++rr) {                                       \
            const int r = g4 * 4 + rr;                                         \
            float sc = fmaf(-2.f, acc[r],                                      \
                rr == 0 ? s4[g4].x : rr == 1 ? s4[g4].y :                      \
                rr == 2 ? s4[g4].z : s4[g4].w);                                \
            sc = __uint_as_float((__float_as_uint(sc) & 0xFFFFFF00u) |         \
                                 (ebase + (unsigned)((r & 3) + 4 * (r >> 2)))); \
            if (selfstep) {                                                    \
                const int rowr = (r & 3) + 8 * (r >> 2) + 4 * lh;              \
                sc = (rowr == q31) ? 1e30f : sc;                               \
            }                                                                  \
            insert6f(sc, dl);                                                  \
        }                                                                      \
    }                                                                          \
} while (0)

    STAGE(0);                               // prologue: step 0 in flight
    int jb = jbeg, cur = 0, nxt = 1;
#pragma unroll 1
    for (int st = 0; st < 15; ++st) {
#pragma unroll
        for (int g4 = 0; g4 < 4; ++g4) s4[g4] = *(const float4*)(sqp + g4 * 8);
        asm volatile("" ::: "memory");      // pin: sq loads issue BEFORE stage
        STAGE(nxt);                         // step st+1 in flight
        if constexpr (C == 32) asm volatile("s_waitcnt vmcnt(5)" ::: "memory");
        else                   asm volatile("s_waitcnt vmcnt(6)" ::: "memory");
        __builtin_amdgcn_s_barrier();       // step-st data landed (all waves)
        COMPUTE(cur, jb);
        jb += 32; sqp += 32;
        cur = nxt;
        nxt = (nxt == 2) ? 0 : nxt + 1;
    }
    {   // epilogue: last step, drain
#pragma unroll
        for (int g4 = 0; g4 < 4; ++g4) s4[g4] = *(const float4*)(sqp + g4 * 8);
        asm volatile("s_waitcnt vmcnt(0)" ::: "memory");
        __builtin_amdgcn_s_barrier();
        COMPUTE(cur, jb);
    }
#undef STAGE
#undef COMPUTE

    // write this lane's sorted sublist as sortable-transformed u32 keys
    unsigned* o = plist + (size_t)(base + qloc) * 48 + (sp * 2 + lh) * 6;
#pragma unroll
    for (int k = 0; k < 6; ++k) {
        const unsigned bits = __float_as_uint(dl[k]);
        o[k] = bits ^ ((bits & 0x80000000u) ? 0xFFFFFFFFu : 0x80000000u);
    }
}

// ---------------- FUSED rescore + edge MLP ----------------
// Phase R (tid<128; 2 thr/query x the block's 64 queries = 1024 working
// waves device-wide, same as standalone rescore): verbatim R19 rescore body,
// nbr written to LDS (never to global -- mlp is its only consumer).
// __syncthreads. Phase M: verbatim R19 mlp body reading j from LDS.
// Removes 3 launches + bubbles + the nbr global round-trip (R19's proven
// fusion mechanism). MINW lowered (4 / 3) to keep the rescore phase's
// qv[C] row under the VGPR cap -- no spill (session failure mode #1).
template<int C, int COUT, bool RESID, int MINW>
__global__ __launch_bounds__(768, MINW)
void mlp_rescore(const float* __restrict__ x, const float* __restrict__ sqv,
                 const unsigned* __restrict__ plist,
                 const float* __restrict__ AB,
                 const float* __restrict__ W2, const float* __restrict__ b2,
                 const float* __restrict__ resid, float* __restrict__ out) {
    constexpr int HALF = COUT / 2;
    constexpr int NQ   = COUT / 4;
    constexpr int N2   = 2 * COUT;
    constexpr int RS = HALF + 4;
    __shared__ float Buf[2][3][64][RS];
    __shared__ int nbrL[64][6];

    const int tid  = threadIdx.x;
    const int lane = tid & 63;
    const int bid  = blockIdx.x;
    const int bsw  = ((bid & 7) << 6) | (bid >> 3);             // XCD swizzle, 512 blocks
    const int i    = bsw * 64 + lane;

    // ---- phase R: rescore the block's 64 queries (tid < 128) ----
    if (tid < 128) {
        const int ql   = tid >> 1;                              // query 0..63
        const int qi   = bsw * 64 + ql;
        const int slot = tid & 1;
        const unsigned* pr = plist + (size_t)qi * 48 + slot * 24;

        unsigned long long best[7];
#pragma unroll
        for (int k = 0; k < 7; ++k) best[k] = ~0ull;
        for (int z4 = 0; z4 < 4; ++z4) {
            const unsigned* p = pr + z4 * 6;
            const unsigned zg = (unsigned)(slot * 4 + z4);
            for (int e = 0; e < 6; ++e) {
                unsigned long long v = ((unsigned long long)p[e] << 3) | zg;
                if (v >= best[6]) break;      // sublist ascending
                best[6] = v;
#pragma unroll
                for (int k = 5; k >= 0; --k) {
                    if (best[k + 1] < best[k]) {
                        unsigned long long t = best[k]; best[k] = best[k + 1]; best[k + 1] = t;
                    }
                }
            }
        }

        const int base = qi & ~(NN - 1);
        float4 qv[C / 4];
        const float4* qp = (const float4*)(x + (size_t)qi * C);
#pragma unroll
        for (int t = 0; t < C / 4; ++t) qv[t] = qp[t];

        unsigned long long out6[6];
#pragma unroll
        for (int k = 0; k < 6; ++k) out6[k] = ~0ull;

        for (int mm = 0; mm < 7; ++mm) {
            const unsigned u32k = (unsigned)(best[mm] >> 3);
            const int z = (int)(best[mm] & 7ull);
            const unsigned orig = (u32k & 0x80000000u) ? (u32k ^ 0x80000000u) : ~u32k;
            const int e = (int)(orig & 255u);
            const int idx = e & 15;
            const int jloc = (z >> 1) * (NN / 4) + (e >> 4) * 32 +
                             (idx & 3) + 8 * (idx >> 2) + (z & 1) * 4;

            const float4* cp = (const float4*)(x + (size_t)(base + jloc) * C);
            float d0 = 0.f, d1 = 0.f, d2 = 0.f, d3 = 0.f;
#pragma unroll
            for (int t = 0; t < C / 4; ++t) {
                float4 a = cp[t];
                d0 = fmaf(a.x, qv[t].x, d0);
                d1 = fmaf(a.y, qv[t].y, d1);
                d2 = fmaf(a.z, qv[t].z, d2);
                d3 = fmaf(a.w, qv[t].w, d3);
            }
            const float s = fmaf(-2.f, (d0 + d1) + (d2 + d3), sqv[base + jloc]);
            unsigned u = __float_as_uint(s);
            u ^= (u & 0x80000000u) ? 0xFFFFFFFFu : 0x80000000u;
            unsigned long long key = ((unsigned long long)u << 11) | (unsigned)jloc;
#pragma unroll
            for (int k = 0; k < 6; ++k) {
                const unsigned long long ok = out6[k];
                const bool c = key < ok;
                out6[k] = c ? key : ok;
                key     = c ? ok  : key;
            }
        }

        // exchange per-half exact top-6 with partner; merge to final top-6
        unsigned long long fin[6];
#pragma unroll
        for (int k = 0; k < 6; ++k) fin[k] = out6[k];
#pragma unroll
        for (int k = 0; k < 6; ++k) {
            const unsigned long long v = out6[k];
            const unsigned lo = __shfl_xor((unsigned)v, 1);
            const unsigned hi = __shfl_xor((unsigned)(v >> 32), 1);
            unsigned long long key = ((unsigned long long)hi << 32) | lo;
#pragma unroll
            for (int q = 0; q < 6; ++q) {
                const unsigned long long ok = fin[q];
                const bool c = key < ok;
                fin[q] = c ? key : ok;
                key    = c ? ok  : key;
            }
        }
#pragma unroll
        for (int k = 0; k < 3; ++k)
            nbrL[ql][slot * 3 + k] = base + (int)(fin[slot * 3 + k] & 2047ull);
    }
    __syncthreads();

    // ---- phase M: edge MLP (verbatim R19 body, j from LDS) ----
    const int wv   = __builtin_amdgcn_readfirstlane(tid >> 6);  // 0..11
    const int oh   = wv / 6;                                    // output half
    const int w6   = wv % 6;                                    // neighbor
    const int j    = nbrL[lane][w6];

    f32x2 uacc[HALF / 2];
#pragma unroll
    for (int o = 0; o < HALF / 2; ++o) uacc[o] = (f32x2){0.f, 0.f};

    cfloat* W2c = (cfloat*)(uintptr_t)W2;
    const float* Ap = AB + (size_t)i * N2;
    const float* Bp = AB + (size_t)j * N2 + COUT;

    const int qofs = (wv * 3) & (NQ - 1);    // wave-staggered op start

#pragma unroll 2
    for (int qi2 = 0; qi2 < NQ; ++qi2) {
        const int oq = (qi2 + qofs) & (NQ - 1);
        const float4 a4 = *(const float4*)(Ap + 4 * oq);
        const float4 b4 = *(const float4*)(Bp + 4 * oq);
#pragma unroll
        for (int rr = 0; rr < 4; ++rr) {
            const int op = oq * 4 + rr;
            const float aop = rr == 0 ? a4.x : rr == 1 ? a4.y : rr == 2 ? a4.z : a4.w;
            const float bop = rr == 0 ? b4.x : rr == 1 ? b4.y : rr == 2 ? b4.z : b4.w;
            const float h = fmaxf(aop + bop, 0.f);
            cf32x2* w2p = (cf32x2*)(W2c + (size_t)op * COUT + oh * HALF);
            const f32x2 hv = {h, h};
#pragma unroll
            for (int o = 0; o < HALF / 2; ++o)
                uacc[o] += w2p[o] * hv;          // v_pk_fma_f32
        }
    }

    // per-half 6 -> 1 max tree over neighbor waves
    if (w6 >= 3) {
#pragma unroll
        for (int o = 0; o < HALF / 2; ++o) {
            Buf[oh][w6 - 3][lane][2 * o]     = uacc[o].x;
            Buf[oh][w6 - 3][lane][2 * o + 1] = uacc[o].y;
        }
    }
    __syncthreads();
    if (w6 < 3) {
#pragma unroll
        for (int o = 0; o < HALF / 2; ++o) {
            uacc[o].x = fmaxf(uacc[o].x, Buf[oh][w6][lane][2 * o]);
            uacc[o].y = fmaxf(uacc[o].y, Buf[oh][w6][lane][2 * o + 1]);
        }
    }
    __syncthreads();
    if (w6 == 1 || w6 == 2) {
#pragma unroll
        for (int o = 0; o < HALF / 2; ++o) {
            Buf[oh][w6][lane][2 * o]     = uacc[o].x;
            Buf[oh][w6][lane][2 * o + 1] = uacc[o].y;
        }
    }
    __syncthreads();
    if (w6 == 0) {
        float* po = out + (size_t)i * COUT + oh * HALF;
        const float* b2p = b2 + oh * HALF;
        const float* rp  = RESID ? (resid + (size_t)i * COUT + oh * HALF) : nullptr;
#pragma unroll
        for (int o = 0; o < HALF / 2; ++o) {
            float v0 = fmaxf(uacc[o].x,
                             fmaxf(Buf[oh][1][lane][2 * o], Buf[oh][2][lane][2 * o])) + b2p[2 * o];
            float v1 = fmaxf(uacc[o].y,
                             fmaxf(Buf[oh][1][lane][2 * o + 1], Buf[oh][2][lane][2 * o + 1])) + b2p[2 * o + 1];
            if (RESID) { v0 += rp[2 * o]; v1 += rp[2 * o + 1]; }
            po[2 * o]     = fmaxf(v0, 0.f);
            po[2 * o + 1] = fmaxf(v1, 0.f);
        }
    }
}

extern "C" void kernel_launch(void* const* d_in, const int* in_sizes, int n_in,
                              void* d_out, int out_size, void* d_ws, size_t ws_size,
                              hipStream_t stream) {
    const float* x    = (const float*)d_in[0];
    const float* W1_0 = (const float*)d_in[2];
    const float* b1_0 = (const float*)d_in[3];
    const float* W2_0 = (const float*)d_in[4];
    const float* b2_0 = (const float*)d_in[5];
    const float* W1_1 = (const float*)d_in[6];
    const float* b1_1 = (const float*)d_in[7];
    const float* W2_1 = (const float*)d_in[8];
    const float* b2_1 = (const float*)d_in[9];
    const float* W1_2 = (const float*)d_in[10];
    const float* b1_2 = (const float*)d_in[11];
    const float* W2_2 = (const float*)d_in[12];
    const float* b2_2 = (const float*)d_in[13];
    float* outp = (float*)d_out;

    // workspace layout
    unsigned* plist = (unsigned*)d_ws;                            // NPTS*48 u32
    float* x0  = (float*)(plist + (size_t)NPTS * 48);             // 32768 x 64
    float* x1  = x0 + (size_t)NPTS * 64;                          // 32768 x 32
    float* sqb = x1 + (size_t)NPTS * 32;                          // 32768
    unsigned short* Whi0 = (unsigned short*)(sqb + NPTS);         // 6 x 4096 u16
    unsigned short* Wlo0 = Whi0 + 4096;
    unsigned short* Whi1 = Wlo0 + 4096;
    unsigned short* Wlo1 = Whi1 + 4096;
    unsigned short* Whi2 = Wlo1 + 4096;
    unsigned short* Wlo2 = Whi2 + 4096;
    unsigned short* Xhi = Wlo2 + 4096;                            // 32768 x 64 u16
    unsigned short* Xlo = Xhi + (size_t)NPTS * 64;                // 32768 x 64 u16
    float* AB = (float*)(Xlo + (size_t)NPTS * 64);                // 32768 x 128

    const int scgrid = 1024;            // 4096 waves of 32q x 512c
    const int pgrid  = NPTS / 64;       // 512 blocks x 768 thr

    prep_w<<<16, 256, 0, stream>>>(W1_0, W1_1, W1_2, Whi0, Wlo0, Whi1, Wlo1, Whi2, Wlo2);

    // ---- layer 0: x (32) -> x0 (64), relu ----
    prep_gemm<32, 64><<<NPTS / 32, 256, 0, stream>>>(x, Whi0, Wlo0, b1_0, Xhi, Xlo, sqb, AB);
    knn_scan<32><<<scgrid, 256, 0, stream>>>(Xhi, Xlo, sqb, plist);
    mlp_rescore<32, 64, false, 4><<<pgrid, 768, 0, stream>>>(x, sqb, plist, AB, W2_0, b2_0, nullptr, x0);

    // ---- layer 1: x0 (64) -> x1 (32), relu ----
    prep_gemm<64, 32><<<NPTS / 64, 256, 0, stream>>>(x0, Whi1, Wlo1, b1_1, Xhi, Xlo, sqb, AB);
    knn_scan<64><<<scgrid, 256, 0, stream>>>(Xhi, Xlo, sqb, plist);
    mlp_rescore<64, 32, false, 3><<<pgrid, 768, 0, stream>>>(x0, sqb, plist, AB, W2_1, b2_1, nullptr, x1);

    // ---- layer 2: x1 (32) -> out (64), +x0 residual, relu ----
    prep_gemm<32, 64><<<NPTS / 32, 256, 0, stream>>>(x1, Whi2, Wlo2, b1_2, Xhi, Xlo, sqb, AB);
    knn_scan<32><<<scgrid, 256, 0, stream>>>(Xhi, Xlo, sqb, plist);
    mlp_rescore<32, 64, true, 4><<<pgrid, 768, 0, stream>>>(x1, sqb, plist, AB, W2_2, b2_2, x0, outp);
}